// Round 2
// baseline (1206.787 us; speedup 1.0000x reference)
//
#include <hip/hip_runtime.h>
#include <hip/hip_bf16.h>

#define NU 262144
#define GG 128
#define PG 134          // padded field side (128 + 2*3)
#define DD 128

typedef __attribute__((ext_vector_type(8))) short short8;   // 8 bf16 (4 VGPR) MFMA frag
typedef __attribute__((ext_vector_type(4))) float f32x4;
typedef __attribute__((ext_vector_type(4))) int int4v;

// fp32 -> bf16, round-to-nearest-even
__device__ __forceinline__ unsigned short f2b(float f) {
  union { float f; unsigned u; } v; v.f = f;
  unsigned r = v.u + 0x7fffu + ((v.u >> 16) & 1u);
  return (unsigned short)(r >> 16);
}

__device__ __forceinline__ float fast_tanh(float x) {
  float ax = fabsf(x);
  float e  = __expf(ax + ax);
  float t  = 1.0f - __fdividef(2.0f, e + 1.0f);
  return copysignf(t, x);
}

// neighborhood offset -> flat delta in padded 134^3 field
struct alignas(16) DoffT { int v[128]; };
static constexpr DoffT mkdoff() {
  DoffT t{};
  for (int d = 0; d < 128; ++d) {
    int i = d / 49, r = d % 49, j = r / 7, k = r % 7;
    t.v[d] = ((i - 3) * PG + (j - 3)) * PG + (k - 3);
  }
  return t;
}
__device__ constexpr DoffT DOFF = mkdoff();

// ---------------- prep 1: clamped pad + bf16 convert of the field ----------------
__global__ void prep_field(const float* __restrict__ f, unsigned short* __restrict__ fp) {
  int idx = blockIdx.x * 256 + threadIdx.x;
  if (idx >= PG * PG * PG) return;
  int z = idx % PG, t = idx / PG;
  int y = t % PG, x = t / PG;
  int xx = min(max(x - 3, 0), GG - 1);
  int yy = min(max(y - 3, 0), GG - 1);
  int zz = min(max(z - 3, 0), GG - 1);
  fp[idx] = f2b(f[(xx * GG + yy) * GG + zz]);
}

// ---------------- prep 2: W1/W2 -> frag-major bf16 ----------------
__global__ void prep_w(const float* __restrict__ W1, const float* __restrict__ W2,
                       unsigned short* __restrict__ w1t, unsigned short* __restrict__ w2t) {
  int idx = blockIdx.x * 256 + threadIdx.x;   // one 16B frag-chunk per thread
  if (idx < 4096) {                            // W1: 8 kt * 8 nt * 64 lanes
    int kt = idx >> 9, nt = (idx >> 6) & 7, ln = idx & 63;
    int n = nt * 16 + (ln & 15), k0 = kt * 32 + (ln >> 4) * 8;
    short8 s;
#pragma unroll
    for (int j = 0; j < 8; ++j) s[j] = (short)f2b(W1[(k0 + j) * DD + n]);
    ((short8*)w1t)[idx] = s;
  } else if (idx < 6144) {                     // W2: 4 kt * 8 nt * 64 lanes
    int c = idx - 4096;
    int kt = c >> 9, nt = (c >> 6) & 7, ln = c & 63;
    int n = nt * 16 + (ln & 15), k0 = kt * 32 + (ln >> 4) * 8;
    short8 s;
#pragma unroll
    for (int j = 0; j < 8; ++j) s[j] = (short)f2b(W2[(k0 + j) * DD + n]);
    ((short8*)w2t)[c] = s;
  }
}

// ---------------- main kernel: 4 waves * 32 units per block (128 units/block) ----------------
__global__ __launch_bounds__(256, 4) void atu_main(
    const float* __restrict__ pos, const float* __restrict__ sig,
    const float* __restrict__ offs, const float* __restrict__ b1,
    const float* __restrict__ b2, const unsigned short* __restrict__ fpad,
    const short8* __restrict__ w1f, const short8* __restrict__ w2f,
    float* __restrict__ out_stab, float* __restrict__ out_pos)
{
  __shared__ unsigned short hs[4][4096];     // 8KB per wave, 32KB total
  const int tid  = threadIdx.x;
  const int wid  = tid >> 6, lane = tid & 63;
  const int lg   = lane >> 4, lm = lane & 15;
  const int ubase = blockIdx.x * 128 + wid * 32;
  char* hsb = (char*)&hs[wid][0];

  float ssqe[2];

#pragma unroll 1
  for (int ev = 0; ev < 2; ++ev) {
    // ---- per-unit-tile gather bases (padded coords, no clamps needed later) ----
    int abase[2];
#pragma unroll
    for (int ut = 0; ut < 2; ++ut) {
      int u = ubase + ut * 16 + lm;
      float px = pos[u * 3 + 0], py = pos[u * 3 + 1], pz = pos[u * 3 + 2];
      if (ev) { px += offs[u * 3 + 0]; py += offs[u * 3 + 1]; pz += offs[u * 3 + 2]; }
      int pcx = min(max((int)px, 0), GG - 1);
      int pcy = min(max((int)py, 0), GG - 1);
      int pcz = min(max((int)pz, 0), GG - 1);
      abase[ut] = ((pcx + 3) * PG + (pcy + 3)) * PG + (pcz + 3);
    }

    // ---- GEMM1: hT[128 feat][32 units] += W1t x combinedT ----
    f32x4 acc[8][2];
#pragma unroll
    for (int nt = 0; nt < 8; ++nt)
#pragma unroll
      for (int ut = 0; ut < 2; ++ut) acc[nt][ut] = f32x4{0.f, 0.f, 0.f, 0.f};

#pragma unroll
    for (int kt = 0; kt < 4; ++kt) {          // signature half (k = 0..127)
      short8 bfr[2];
#pragma unroll
      for (int ut = 0; ut < 2; ++ut) {
        int u = ubase + ut * 16 + lm;
        const f32x4* sp = (const f32x4*)(sig + (u * DD + kt * 32 + lg * 8));
        f32x4 s0 = sp[0], s1 = sp[1];
        short8 fr;
        fr[0] = (short)f2b(s0[0]); fr[1] = (short)f2b(s0[1]);
        fr[2] = (short)f2b(s0[2]); fr[3] = (short)f2b(s0[3]);
        fr[4] = (short)f2b(s1[0]); fr[5] = (short)f2b(s1[1]);
        fr[6] = (short)f2b(s1[2]); fr[7] = (short)f2b(s1[3]);
        bfr[ut] = fr;
      }
#pragma unroll
      for (int nt = 0; nt < 8; ++nt) {
        short8 af = w1f[(kt * 8 + nt) * 64 + lane];
#pragma unroll
        for (int ut = 0; ut < 2; ++ut)
          acc[nt][ut] = __builtin_amdgcn_mfma_f32_16x16x32_bf16(af, bfr[ut], acc[nt][ut], 0, 0, 0);
      }
    }

#pragma unroll
    for (int kt = 4; kt < 8; ++kt) {          // gathered-local half (k = 128..255)
      int d0 = (kt - 4) * 32 + lg * 8;
      int4v dv0 = *(const int4v*)&DOFF.v[d0];
      int4v dv1 = *(const int4v*)&DOFF.v[d0 + 4];
      short8 bfr[2];
#pragma unroll
      for (int ut = 0; ut < 2; ++ut) {
        int ab = abase[ut];
        short8 fr;
        fr[0] = (short)fpad[ab + dv0[0]]; fr[1] = (short)fpad[ab + dv0[1]];
        fr[2] = (short)fpad[ab + dv0[2]]; fr[3] = (short)fpad[ab + dv0[3]];
        fr[4] = (short)fpad[ab + dv1[0]]; fr[5] = (short)fpad[ab + dv1[1]];
        fr[6] = (short)fpad[ab + dv1[2]]; fr[7] = (short)fpad[ab + dv1[3]];
        bfr[ut] = fr;
      }
#pragma unroll
      for (int nt = 0; nt < 8; ++nt) {
        short8 af = w1f[(kt * 8 + nt) * 64 + lane];
#pragma unroll
        for (int ut = 0; ut < 2; ++ut)
          acc[nt][ut] = __builtin_amdgcn_mfma_f32_16x16x32_bf16(af, bfr[ut], acc[nt][ut], 0, 0, 0);
      }
    }

    // ---- bias + tanh + write h to swizzled per-wave LDS (transpose) ----
#pragma unroll
    for (int nt = 0; nt < 8; ++nt) {
      f32x4 b1v = *(const f32x4*)(b1 + nt * 16 + lg * 4);
#pragma unroll
      for (int ut = 0; ut < 2; ++ut) {
        int u = ut * 16 + lm;
        float h0 = fast_tanh(acc[nt][ut][0] + b1v[0]);
        float h1 = fast_tanh(acc[nt][ut][1] + b1v[1]);
        float h2 = fast_tanh(acc[nt][ut][2] + b1v[2]);
        float h3 = fast_tanh(acc[nt][ut][3] + b1v[3]);
        unsigned q0 = (unsigned)f2b(h0) | ((unsigned)f2b(h1) << 16);
        unsigned q1 = (unsigned)f2b(h2) | ((unsigned)f2b(h3) << 16);
        int byte = (u * 256 + nt * 32 + lg * 8) ^ ((u & 7) << 4);
        *(unsigned long long*)(hsb + byte) =
            (unsigned long long)q0 | ((unsigned long long)q1 << 32);
      }
    }

    // ---- GEMM2: respT[128 feat][32 units] = W2t x hT ----
    f32x4 acc2[8][2];
#pragma unroll
    for (int nt = 0; nt < 8; ++nt)
#pragma unroll
      for (int ut = 0; ut < 2; ++ut) acc2[nt][ut] = f32x4{0.f, 0.f, 0.f, 0.f};

#pragma unroll
    for (int kt = 0; kt < 4; ++kt) {
      short8 hfr[2];
#pragma unroll
      for (int ut = 0; ut < 2; ++ut) {
        int u = ut * 16 + lm;
        int byte = (u * 256 + kt * 64 + lg * 16) ^ ((u & 7) << 4);
        hfr[ut] = *(const short8*)(hsb + byte);
      }
#pragma unroll
      for (int nt = 0; nt < 8; ++nt) {
        short8 af = w2f[(kt * 8 + nt) * 64 + lane];
#pragma unroll
        for (int ut = 0; ut < 2; ++ut)
          acc2[nt][ut] = __builtin_amdgcn_mfma_f32_16x16x32_bf16(af, hfr[ut], acc2[nt][ut], 0, 0, 0);
      }
    }

    // ---- || resp - sig ||^2 ----
    float ssq[2] = {0.f, 0.f};
#pragma unroll
    for (int nt = 0; nt < 8; ++nt) {
      f32x4 b2v = *(const f32x4*)(b2 + nt * 16 + lg * 4);
#pragma unroll
      for (int ut = 0; ut < 2; ++ut) {
        int u = ubase + ut * 16 + lm;
        f32x4 sv = *(const f32x4*)(sig + (u * DD + nt * 16 + lg * 4));
#pragma unroll
        for (int r = 0; r < 4; ++r) {
          float d = acc2[nt][ut][r] + b2v[r] - sv[r];
          ssq[ut] = fmaf(d, d, ssq[ut]);
        }
      }
    }
#pragma unroll
    for (int ut = 0; ut < 2; ++ut) {
      ssq[ut] += __shfl_xor(ssq[ut], 16, 64);
      ssq[ut] += __shfl_xor(ssq[ut], 32, 64);
    }
    ssqe[ev] = (lane & 16) ? ssq[1] : ssq[0];
  }

  // ---- accept / outputs: lane l (<32) owns unit ubase + l ----
  if (lane < 32) {
    int ul = ubase + lane;
    float px = pos[ul * 3 + 0], py = pos[ul * 3 + 1], pz = pos[ul * 3 + 2];
    float ox = offs[ul * 3 + 0], oy = offs[ul * 3 + 1], oz = offs[ul * 3 + 2];
    bool ok = ssqe[1] <= ssqe[0];
    out_stab[ul] = sqrtf(ok ? ssqe[1] : ssqe[0]);
    out_pos[ul * 3 + 0] = ok ? px + ox : px;
    out_pos[ul * 3 + 1] = ok ? py + oy : py;
    out_pos[ul * 3 + 2] = ok ? pz + oz : pz;
  }
}

extern "C" void kernel_launch(void* const* d_in, const int* in_sizes, int n_in,
                              void* d_out, int out_size, void* d_ws, size_t ws_size,
                              hipStream_t stream) {
  const float* field = (const float*)d_in[0];
  const float* pos   = (const float*)d_in[1];
  const float* sig   = (const float*)d_in[2];
  const float* offs  = (const float*)d_in[3];
  const float* W1    = (const float*)d_in[4];
  const float* b1    = (const float*)d_in[5];
  const float* W2    = (const float*)d_in[6];
  const float* b2    = (const float*)d_in[7];
  float* out_stab = (float*)d_out;
  float* out_pos  = out_stab + NU;

  char* ws = (char*)d_ws;
  // ws layout: [0, 4812208) padded bf16 field; then frag-major weights
  unsigned short* fpad = (unsigned short*)ws;
  unsigned short* w1t  = (unsigned short*)(ws + 4812800);
  unsigned short* w2t  = (unsigned short*)(ws + 4878336);

  prep_field<<<(PG * PG * PG + 255) / 256, 256, 0, stream>>>(field, fpad);
  prep_w<<<24, 256, 0, stream>>>(W1, W2, w1t, w2t);
  atu_main<<<NU / 128, 256, 0, stream>>>(pos, sig, offs, b1, b2, fpad,
                                         (const short8*)w1t, (const short8*)w2t,
                                         out_stab, out_pos);
}

// Round 3
// 997.788 us; speedup vs baseline: 1.2095x; 1.2095x over previous
//
#include <hip/hip_runtime.h>
#include <hip/hip_bf16.h>

#define NU 262144
#define GG 128
#define PG 134          // padded field side (128 + 2*3)
#define DD 128

typedef __attribute__((ext_vector_type(8))) short short8;   // 8 bf16 (4 VGPR) MFMA frag
typedef __attribute__((ext_vector_type(4))) float f32x4;
typedef __attribute__((ext_vector_type(4))) int int4v;

// fp32 -> bf16, round-to-nearest-even
__device__ __forceinline__ unsigned short f2b(float f) {
  union { float f; unsigned u; } v; v.f = f;
  unsigned r = v.u + 0x7fffu + ((v.u >> 16) & 1u);
  return (unsigned short)(r >> 16);
}

__device__ __forceinline__ float fast_tanh(float x) {
  float ax = fabsf(x);
  float e  = __expf(ax + ax);
  float t  = 1.0f - __fdividef(2.0f, e + 1.0f);
  return copysignf(t, x);
}

// neighborhood offset -> flat delta in padded 134^3 field
struct alignas(16) DoffT { int v[128]; };
static constexpr DoffT mkdoff() {
  DoffT t{};
  for (int d = 0; d < 128; ++d) {
    int i = d / 49, r = d % 49, j = r / 7, k = r % 7;
    t.v[d] = ((i - 3) * PG + (j - 3)) * PG + (k - 3);
  }
  return t;
}
__device__ constexpr DoffT DOFF = mkdoff();

// ---------------- prep 1: clamped pad + bf16 convert of the field ----------------
__global__ void prep_field(const float* __restrict__ f, unsigned short* __restrict__ fp) {
  int idx = blockIdx.x * 256 + threadIdx.x;
  if (idx >= PG * PG * PG) return;
  int z = idx % PG, t = idx / PG;
  int y = t % PG, x = t / PG;
  int xx = min(max(x - 3, 0), GG - 1);
  int yy = min(max(y - 3, 0), GG - 1);
  int zz = min(max(z - 3, 0), GG - 1);
  fp[idx] = f2b(f[(xx * GG + yy) * GG + zz]);
}

// ---------------- prep 2: W1/W2 -> frag-major bf16 ----------------
__global__ void prep_w(const float* __restrict__ W1, const float* __restrict__ W2,
                       unsigned short* __restrict__ w1t, unsigned short* __restrict__ w2t) {
  int idx = blockIdx.x * 256 + threadIdx.x;   // one 16B frag-chunk per thread
  if (idx < 4096) {                            // W1: 8 kt * 8 nt * 64 lanes
    int kt = idx >> 9, nt = (idx >> 6) & 7, ln = idx & 63;
    int n = nt * 16 + (ln & 15), k0 = kt * 32 + (ln >> 4) * 8;
    short8 s;
#pragma unroll
    for (int j = 0; j < 8; ++j) s[j] = (short)f2b(W1[(k0 + j) * DD + n]);
    ((short8*)w1t)[idx] = s;
  } else if (idx < 6144) {                     // W2: 4 kt * 8 nt * 64 lanes
    int c = idx - 4096;
    int kt = c >> 9, nt = (c >> 6) & 7, ln = c & 63;
    int n = nt * 16 + (ln & 15), k0 = kt * 32 + (ln >> 4) * 8;
    short8 s;
#pragma unroll
    for (int j = 0; j < 8; ++j) s[j] = (short)f2b(W2[(k0 + j) * DD + n]);
    ((short8*)w2t)[c] = s;
  }
}

// ---------------- main kernel: 4 waves * 32 units per block (128 units/block) ----------------
// waves_per_eu(4,4): pin the 128-VGPR tier; stop the spill-for-occupancy heuristic.
__global__ __attribute__((amdgpu_waves_per_eu(4, 4))) __launch_bounds__(256)
void atu_main(
    const float* __restrict__ pos, const float* __restrict__ sig,
    const float* __restrict__ offs, const float* __restrict__ b1,
    const float* __restrict__ b2, const unsigned short* __restrict__ fpad,
    const short8* __restrict__ w1f, const short8* __restrict__ w2f,
    float* __restrict__ out_stab, float* __restrict__ out_pos)
{
  __shared__ unsigned short hs[4][4096];     // 8KB per wave, 32KB total
  const int tid  = threadIdx.x;
  const int wid  = tid >> 6, lane = tid & 63;
  const int lg   = lane >> 4, lm = lane & 15;
  const int ubase = blockIdx.x * 128 + wid * 32;
  char* hsb = (char*)&hs[wid][0];

  float ssqe[2];

#pragma unroll 1
  for (int ev = 0; ev < 2; ++ev) {
    // ---- per-unit-tile gather bases (padded coords, no clamps needed later) ----
    int abase[2];
#pragma unroll
    for (int ut = 0; ut < 2; ++ut) {
      int u = ubase + ut * 16 + lm;
      float px = pos[u * 3 + 0], py = pos[u * 3 + 1], pz = pos[u * 3 + 2];
      if (ev) { px += offs[u * 3 + 0]; py += offs[u * 3 + 1]; pz += offs[u * 3 + 2]; }
      int pcx = min(max((int)px, 0), GG - 1);
      int pcy = min(max((int)py, 0), GG - 1);
      int pcz = min(max((int)pz, 0), GG - 1);
      abase[ut] = ((pcx + 3) * PG + (pcy + 3)) * PG + (pcz + 3);
    }

    // ---- GEMM1: hT[128 feat][32 units] += W1t x combinedT ----
    f32x4 acc[8][2];
#pragma unroll
    for (int nt = 0; nt < 8; ++nt)
#pragma unroll
      for (int ut = 0; ut < 2; ++ut) acc[nt][ut] = f32x4{0.f, 0.f, 0.f, 0.f};

#pragma unroll
    for (int kt = 0; kt < 4; ++kt) {          // signature half (k = 0..127)
      short8 bfr[2];
#pragma unroll
      for (int ut = 0; ut < 2; ++ut) {
        int u = ubase + ut * 16 + lm;
        const f32x4* sp = (const f32x4*)(sig + (u * DD + kt * 32 + lg * 8));
        f32x4 s0 = sp[0], s1 = sp[1];
        short8 fr;
        fr[0] = (short)f2b(s0[0]); fr[1] = (short)f2b(s0[1]);
        fr[2] = (short)f2b(s0[2]); fr[3] = (short)f2b(s0[3]);
        fr[4] = (short)f2b(s1[0]); fr[5] = (short)f2b(s1[1]);
        fr[6] = (short)f2b(s1[2]); fr[7] = (short)f2b(s1[3]);
        bfr[ut] = fr;
      }
#pragma unroll
      for (int nt = 0; nt < 8; ++nt) {
        short8 af = w1f[(kt * 8 + nt) * 64 + lane];
#pragma unroll
        for (int ut = 0; ut < 2; ++ut)
          acc[nt][ut] = __builtin_amdgcn_mfma_f32_16x16x32_bf16(af, bfr[ut], acc[nt][ut], 0, 0, 0);
      }
    }

#pragma unroll
    for (int kt = 4; kt < 8; ++kt) {          // gathered-local half (k = 128..255)
      int d0 = (kt - 4) * 32 + lg * 8;
      int4v dv0 = *(const int4v*)&DOFF.v[d0];
      int4v dv1 = *(const int4v*)&DOFF.v[d0 + 4];
      short8 bfr[2];
#pragma unroll
      for (int ut = 0; ut < 2; ++ut) {
        int ab = abase[ut];
        short8 fr;
        fr[0] = (short)fpad[ab + dv0[0]]; fr[1] = (short)fpad[ab + dv0[1]];
        fr[2] = (short)fpad[ab + dv0[2]]; fr[3] = (short)fpad[ab + dv0[3]];
        fr[4] = (short)fpad[ab + dv1[0]]; fr[5] = (short)fpad[ab + dv1[1]];
        fr[6] = (short)fpad[ab + dv1[2]]; fr[7] = (short)fpad[ab + dv1[3]];
        bfr[ut] = fr;
      }
#pragma unroll
      for (int nt = 0; nt < 8; ++nt) {
        short8 af = w1f[(kt * 8 + nt) * 64 + lane];
#pragma unroll
        for (int ut = 0; ut < 2; ++ut)
          acc[nt][ut] = __builtin_amdgcn_mfma_f32_16x16x32_bf16(af, bfr[ut], acc[nt][ut], 0, 0, 0);
      }
    }

    // ---- bias + tanh + write h to swizzled per-wave LDS (transpose) ----
#pragma unroll
    for (int nt = 0; nt < 8; ++nt) {
      f32x4 b1v = *(const f32x4*)(b1 + nt * 16 + lg * 4);
#pragma unroll
      for (int ut = 0; ut < 2; ++ut) {
        int u = ut * 16 + lm;
        float h0 = fast_tanh(acc[nt][ut][0] + b1v[0]);
        float h1 = fast_tanh(acc[nt][ut][1] + b1v[1]);
        float h2 = fast_tanh(acc[nt][ut][2] + b1v[2]);
        float h3 = fast_tanh(acc[nt][ut][3] + b1v[3]);
        unsigned q0 = (unsigned)f2b(h0) | ((unsigned)f2b(h1) << 16);
        unsigned q1 = (unsigned)f2b(h2) | ((unsigned)f2b(h3) << 16);
        int byte = (u * 256 + nt * 32 + lg * 8) ^ ((u & 7) << 4);
        *(unsigned long long*)(hsb + byte) =
            (unsigned long long)q0 | ((unsigned long long)q1 << 32);
      }
    }

    // ---- GEMM2 in two nt-halves (32-reg accumulator each) + fused norm ----
    float ssq[2] = {0.f, 0.f};
#pragma unroll 1
    for (int half = 0; half < 2; ++half) {
      f32x4 acc2[4][2];
#pragma unroll
      for (int n2 = 0; n2 < 4; ++n2)
#pragma unroll
        for (int ut = 0; ut < 2; ++ut) acc2[n2][ut] = f32x4{0.f, 0.f, 0.f, 0.f};

#pragma unroll
      for (int kt = 0; kt < 4; ++kt) {
        short8 hfr[2];
#pragma unroll
        for (int ut = 0; ut < 2; ++ut) {
          int u = ut * 16 + lm;
          int byte = (u * 256 + kt * 64 + lg * 16) ^ ((u & 7) << 4);
          hfr[ut] = *(const short8*)(hsb + byte);
        }
#pragma unroll
        for (int n2 = 0; n2 < 4; ++n2) {
          int nt = half * 4 + n2;
          short8 af = w2f[(kt * 8 + nt) * 64 + lane];
#pragma unroll
          for (int ut = 0; ut < 2; ++ut)
            acc2[n2][ut] = __builtin_amdgcn_mfma_f32_16x16x32_bf16(af, hfr[ut], acc2[n2][ut], 0, 0, 0);
        }
      }

#pragma unroll
      for (int n2 = 0; n2 < 4; ++n2) {
        int nt = half * 4 + n2;
        f32x4 b2v = *(const f32x4*)(b2 + nt * 16 + lg * 4);
#pragma unroll
        for (int ut = 0; ut < 2; ++ut) {
          int u = ubase + ut * 16 + lm;
          f32x4 sv = *(const f32x4*)(sig + (u * DD + nt * 16 + lg * 4));
#pragma unroll
          for (int r = 0; r < 4; ++r) {
            float d = acc2[n2][ut][r] + b2v[r] - sv[r];
            ssq[ut] = fmaf(d, d, ssq[ut]);
          }
        }
      }
    }

#pragma unroll
    for (int ut = 0; ut < 2; ++ut) {
      ssq[ut] += __shfl_xor(ssq[ut], 16, 64);
      ssq[ut] += __shfl_xor(ssq[ut], 32, 64);
    }
    ssqe[ev] = (lane & 16) ? ssq[1] : ssq[0];
  }

  // ---- accept / outputs: lane l (<32) owns unit ubase + l ----
  if (lane < 32) {
    int ul = ubase + lane;
    float px = pos[ul * 3 + 0], py = pos[ul * 3 + 1], pz = pos[ul * 3 + 2];
    float ox = offs[ul * 3 + 0], oy = offs[ul * 3 + 1], oz = offs[ul * 3 + 2];
    bool ok = ssqe[1] <= ssqe[0];
    out_stab[ul] = sqrtf(ok ? ssqe[1] : ssqe[0]);
    out_pos[ul * 3 + 0] = ok ? px + ox : px;
    out_pos[ul * 3 + 1] = ok ? py + oy : py;
    out_pos[ul * 3 + 2] = ok ? pz + oz : pz;
  }
}

extern "C" void kernel_launch(void* const* d_in, const int* in_sizes, int n_in,
                              void* d_out, int out_size, void* d_ws, size_t ws_size,
                              hipStream_t stream) {
  const float* field = (const float*)d_in[0];
  const float* pos   = (const float*)d_in[1];
  const float* sig   = (const float*)d_in[2];
  const float* offs  = (const float*)d_in[3];
  const float* W1    = (const float*)d_in[4];
  const float* b1    = (const float*)d_in[5];
  const float* W2    = (const float*)d_in[6];
  const float* b2    = (const float*)d_in[7];
  float* out_stab = (float*)d_out;
  float* out_pos  = out_stab + NU;

  char* ws = (char*)d_ws;
  // ws layout: [0, 4812208) padded bf16 field; then frag-major weights
  unsigned short* fpad = (unsigned short*)ws;
  unsigned short* w1t  = (unsigned short*)(ws + 4812800);
  unsigned short* w2t  = (unsigned short*)(ws + 4878336);

  prep_field<<<(PG * PG * PG + 255) / 256, 256, 0, stream>>>(field, fpad);
  prep_w<<<24, 256, 0, stream>>>(W1, W2, w1t, w2t);
  atu_main<<<NU / 128, 256, 0, stream>>>(pos, sig, offs, b1, b2, fpad,
                                         (const short8*)w1t, (const short8*)w2t,
                                         out_stab, out_pos);
}

// Round 4
// 364.218 us; speedup vs baseline: 3.3134x; 2.7395x over previous
//
#include <hip/hip_runtime.h>
#include <hip/hip_bf16.h>

#define NU 262144
#define GG 128
#define PG 134          // padded field side (128 + 2*3)
#define DD 128

typedef __attribute__((ext_vector_type(8))) short short8;   // 8 bf16 (4 VGPR) MFMA frag
typedef __attribute__((ext_vector_type(4))) short short4v;  // 4 bf16
typedef __attribute__((ext_vector_type(4))) float f32x4;
typedef __attribute__((ext_vector_type(4))) int int4v;

// fp32 -> bf16, round-to-nearest-even
__device__ __forceinline__ unsigned short f2b(float f) {
  union { float f; unsigned u; } v; v.f = f;
  unsigned r = v.u + 0x7fffu + ((v.u >> 16) & 1u);
  return (unsigned short)(r >> 16);
}
__device__ __forceinline__ float b2f(unsigned short b) {
  union { unsigned u; float f; } v; v.u = ((unsigned)b) << 16; return v.f;
}

__device__ __forceinline__ float fast_tanh(float x) {
  float ax = fabsf(x);
  float e  = __expf(ax + ax);
  float t  = 1.0f - __fdividef(2.0f, e + 1.0f);
  return copysignf(t, x);
}

// neighborhood offset -> flat delta in padded 134^3 field
struct alignas(16) DoffT { int v[128]; };
static constexpr DoffT mkdoff() {
  DoffT t{};
  for (int d = 0; d < 128; ++d) {
    int i = d / 49, r = d % 49, j = r / 7, k = r % 7;
    t.v[d] = ((i - 3) * PG + (j - 3)) * PG + (k - 3);
  }
  return t;
}
__device__ constexpr DoffT DOFF = mkdoff();

// ---------------- prep 1: clamped pad + bf16 convert of the field ----------------
__global__ void prep_field(const float* __restrict__ f, unsigned short* __restrict__ fp) {
  int idx = blockIdx.x * 256 + threadIdx.x;
  if (idx >= PG * PG * PG) return;
  int z = idx % PG, t = idx / PG;
  int y = t % PG, x = t / PG;
  int xx = min(max(x - 3, 0), GG - 1);
  int yy = min(max(y - 3, 0), GG - 1);
  int zz = min(max(z - 3, 0), GG - 1);
  fp[idx] = f2b(f[(xx * GG + yy) * GG + zz]);
}

// ---------------- prep 2: W1/W2 -> frag-major bf16 ----------------
__global__ void prep_w(const float* __restrict__ W1, const float* __restrict__ W2,
                       unsigned short* __restrict__ w1t, unsigned short* __restrict__ w2t) {
  int idx = blockIdx.x * 256 + threadIdx.x;   // one 16B frag-chunk per thread
  if (idx < 4096) {                            // W1: 8 kt * 8 nt * 64 lanes
    int kt = idx >> 9, nt = (idx >> 6) & 7, ln = idx & 63;
    int n = nt * 16 + (ln & 15), k0 = kt * 32 + (ln >> 4) * 8;
    short8 s;
#pragma unroll
    for (int j = 0; j < 8; ++j) s[j] = (short)f2b(W1[(k0 + j) * DD + n]);
    ((short8*)w1t)[idx] = s;
  } else if (idx < 6144) {                     // W2: 4 kt * 8 nt * 64 lanes
    int c = idx - 4096;
    int kt = c >> 9, nt = (c >> 6) & 7, ln = c & 63;
    int n = nt * 16 + (ln & 15), k0 = kt * 32 + (ln >> 4) * 8;
    short8 s;
#pragma unroll
    for (int j = 0; j < 8; ++j) s[j] = (short)f2b(W2[(k0 + j) * DD + n]);
    ((short8*)w2t)[c] = s;
  }
}

// ---------------- prep 3: signatures fp32 -> bf16 ----------------
__global__ void prep_sig(const float* __restrict__ s, unsigned short* __restrict__ sb) {
  int i = (blockIdx.x * 256 + threadIdx.x) * 8;       // NU*DD = 33554432 elements
  const f32x4* p = (const f32x4*)(s + i);
  f32x4 a = p[0], b = p[1];
  short8 o;
  o[0] = (short)f2b(a[0]); o[1] = (short)f2b(a[1]);
  o[2] = (short)f2b(a[2]); o[3] = (short)f2b(a[3]);
  o[4] = (short)f2b(b[0]); o[5] = (short)f2b(b[1]);
  o[6] = (short)f2b(b[2]); o[7] = (short)f2b(b[3]);
  *(short8*)(sb + i) = o;
}

// ---------------- main kernel: 4 waves * 32 units per block (128 units/block) ----------------
// launch_bounds(256,3): 3 waves/EU tier => ~170-reg unified budget (64 acc + ~90 arch fits).
template<bool SB>
__global__ __launch_bounds__(256, 3) void atu_main(
    const float* __restrict__ pos, const float* __restrict__ sig,
    const unsigned short* __restrict__ sigb,
    const float* __restrict__ offs, const float* __restrict__ b1,
    const float* __restrict__ b2, const unsigned short* __restrict__ fpad,
    const short8* __restrict__ w1f, const short8* __restrict__ w2f,
    float* __restrict__ out_stab, float* __restrict__ out_pos)
{
  __shared__ unsigned short hs[4][4096];     // 8KB per wave, 32KB total
  const int tid  = threadIdx.x;
  const int wid  = tid >> 6, lane = tid & 63;
  const int lg   = lane >> 4, lm = lane & 15;
  const int ubase = blockIdx.x * 128 + wid * 32;
  char* hsb = (char*)&hs[wid][0];

  float ssq0, ssq1;

#pragma unroll 1
  for (int ev = 0; ev < 2; ++ev) {
    // ---- per-unit-tile gather bases (padded coords, no clamps needed later) ----
    int abase[2];
#pragma unroll
    for (int ut = 0; ut < 2; ++ut) {
      int u = ubase + ut * 16 + lm;
      float px = pos[u * 3 + 0], py = pos[u * 3 + 1], pz = pos[u * 3 + 2];
      if (ev) { px += offs[u * 3 + 0]; py += offs[u * 3 + 1]; pz += offs[u * 3 + 2]; }
      int pcx = min(max((int)px, 0), GG - 1);
      int pcy = min(max((int)py, 0), GG - 1);
      int pcz = min(max((int)pz, 0), GG - 1);
      abase[ut] = ((pcx + 3) * PG + (pcy + 3)) * PG + (pcz + 3);
    }

    // ---- GEMM1: hT[128 feat][32 units] += W1t x combinedT ----
    f32x4 acc[8][2];
#pragma unroll
    for (int nt = 0; nt < 8; ++nt)
#pragma unroll
      for (int ut = 0; ut < 2; ++ut) acc[nt][ut] = f32x4{0.f, 0.f, 0.f, 0.f};

#pragma unroll 1
    for (int kt = 0; kt < 4; ++kt) {          // signature half (k = 0..127)
      short8 bfr[2];
#pragma unroll
      for (int ut = 0; ut < 2; ++ut) {
        int u = ubase + ut * 16 + lm;
        if constexpr (SB) {
          bfr[ut] = *(const short8*)(sigb + u * DD + kt * 32 + lg * 8);
        } else {
          const f32x4* sp = (const f32x4*)(sig + (u * DD + kt * 32 + lg * 8));
          f32x4 s0 = sp[0], s1 = sp[1];
          short8 fr;
          fr[0] = (short)f2b(s0[0]); fr[1] = (short)f2b(s0[1]);
          fr[2] = (short)f2b(s0[2]); fr[3] = (short)f2b(s0[3]);
          fr[4] = (short)f2b(s1[0]); fr[5] = (short)f2b(s1[1]);
          fr[6] = (short)f2b(s1[2]); fr[7] = (short)f2b(s1[3]);
          bfr[ut] = fr;
        }
      }
#pragma unroll
      for (int nt = 0; nt < 8; ++nt) {
        short8 af = w1f[(kt * 8 + nt) * 64 + lane];
#pragma unroll
        for (int ut = 0; ut < 2; ++ut)
          acc[nt][ut] = __builtin_amdgcn_mfma_f32_16x16x32_bf16(af, bfr[ut], acc[nt][ut], 0, 0, 0);
      }
    }

#pragma unroll 1
    for (int kt = 4; kt < 8; ++kt) {          // gathered-local half (k = 128..255)
      int d0 = (kt - 4) * 32 + lg * 8;
      int4v dv0 = *(const int4v*)&DOFF.v[d0];
      int4v dv1 = *(const int4v*)&DOFF.v[d0 + 4];
      short8 bfr[2];
#pragma unroll
      for (int ut = 0; ut < 2; ++ut) {
        int ab = abase[ut];
        short8 fr;
        fr[0] = (short)fpad[ab + dv0[0]]; fr[1] = (short)fpad[ab + dv0[1]];
        fr[2] = (short)fpad[ab + dv0[2]]; fr[3] = (short)fpad[ab + dv0[3]];
        fr[4] = (short)fpad[ab + dv1[0]]; fr[5] = (short)fpad[ab + dv1[1]];
        fr[6] = (short)fpad[ab + dv1[2]]; fr[7] = (short)fpad[ab + dv1[3]];
        bfr[ut] = fr;
      }
#pragma unroll
      for (int nt = 0; nt < 8; ++nt) {
        short8 af = w1f[(kt * 8 + nt) * 64 + lane];
#pragma unroll
        for (int ut = 0; ut < 2; ++ut)
          acc[nt][ut] = __builtin_amdgcn_mfma_f32_16x16x32_bf16(af, bfr[ut], acc[nt][ut], 0, 0, 0);
      }
    }

    // ---- bias + tanh + write h to swizzled per-wave LDS (transpose) ----
#pragma unroll
    for (int nt = 0; nt < 8; ++nt) {
      f32x4 b1v = *(const f32x4*)(b1 + nt * 16 + lg * 4);
#pragma unroll
      for (int ut = 0; ut < 2; ++ut) {
        int u = ut * 16 + lm;
        float h0 = fast_tanh(acc[nt][ut][0] + b1v[0]);
        float h1 = fast_tanh(acc[nt][ut][1] + b1v[1]);
        float h2 = fast_tanh(acc[nt][ut][2] + b1v[2]);
        float h3 = fast_tanh(acc[nt][ut][3] + b1v[3]);
        unsigned q0 = (unsigned)f2b(h0) | ((unsigned)f2b(h1) << 16);
        unsigned q1 = (unsigned)f2b(h2) | ((unsigned)f2b(h3) << 16);
        int byte = (u * 256 + nt * 32 + lg * 8) ^ ((u & 7) << 4);
        *(unsigned long long*)(hsb + byte) =
            (unsigned long long)q0 | ((unsigned long long)q1 << 32);
      }
    }

    // ---- GEMM2 in two nt-halves (32-reg accumulator each) + fused norm ----
    float ssq[2] = {0.f, 0.f};
#pragma unroll 1
    for (int half = 0; half < 2; ++half) {
      f32x4 acc2[4][2];
#pragma unroll
      for (int n2 = 0; n2 < 4; ++n2)
#pragma unroll
        for (int ut = 0; ut < 2; ++ut) acc2[n2][ut] = f32x4{0.f, 0.f, 0.f, 0.f};

#pragma unroll 1
      for (int kt = 0; kt < 4; ++kt) {
        short8 hfr[2];
#pragma unroll
        for (int ut = 0; ut < 2; ++ut) {
          int u = ut * 16 + lm;
          int byte = (u * 256 + kt * 64 + lg * 16) ^ ((u & 7) << 4);
          hfr[ut] = *(const short8*)(hsb + byte);
        }
#pragma unroll
        for (int n2 = 0; n2 < 4; ++n2) {
          int nt = half * 4 + n2;
          short8 af = w2f[(kt * 8 + nt) * 64 + lane];
#pragma unroll
          for (int ut = 0; ut < 2; ++ut)
            acc2[n2][ut] = __builtin_amdgcn_mfma_f32_16x16x32_bf16(af, hfr[ut], acc2[n2][ut], 0, 0, 0);
        }
      }

#pragma unroll
      for (int n2 = 0; n2 < 4; ++n2) {
        int nt = half * 4 + n2;
        f32x4 b2v = *(const f32x4*)(b2 + nt * 16 + lg * 4);
#pragma unroll
        for (int ut = 0; ut < 2; ++ut) {
          int u = ubase + ut * 16 + lm;
          float sv0, sv1, sv2, sv3;
          if constexpr (SB) {
            short4v hv = *(const short4v*)(sigb + u * DD + nt * 16 + lg * 4);
            sv0 = b2f((unsigned short)hv[0]); sv1 = b2f((unsigned short)hv[1]);
            sv2 = b2f((unsigned short)hv[2]); sv3 = b2f((unsigned short)hv[3]);
          } else {
            f32x4 sv = *(const f32x4*)(sig + (u * DD + nt * 16 + lg * 4));
            sv0 = sv[0]; sv1 = sv[1]; sv2 = sv[2]; sv3 = sv[3];
          }
          float d0 = acc2[n2][ut][0] + b2v[0] - sv0;
          float d1 = acc2[n2][ut][1] + b2v[1] - sv1;
          float d2 = acc2[n2][ut][2] + b2v[2] - sv2;
          float d3 = acc2[n2][ut][3] + b2v[3] - sv3;
          ssq[ut] = fmaf(d0, d0, ssq[ut]);
          ssq[ut] = fmaf(d1, d1, ssq[ut]);
          ssq[ut] = fmaf(d2, d2, ssq[ut]);
          ssq[ut] = fmaf(d3, d3, ssq[ut]);
        }
      }
    }

#pragma unroll
    for (int ut = 0; ut < 2; ++ut) {
      ssq[ut] += __shfl_xor(ssq[ut], 16, 64);
      ssq[ut] += __shfl_xor(ssq[ut], 32, 64);
    }
    float r = (lane & 16) ? ssq[1] : ssq[0];
    if (ev == 0) ssq0 = r; else ssq1 = r;
  }

  // ---- accept / outputs: lane l (<32) owns unit ubase + l ----
  if (lane < 32) {
    int ul = ubase + lane;
    float px = pos[ul * 3 + 0], py = pos[ul * 3 + 1], pz = pos[ul * 3 + 2];
    float ox = offs[ul * 3 + 0], oy = offs[ul * 3 + 1], oz = offs[ul * 3 + 2];
    bool ok = ssq1 <= ssq0;
    out_stab[ul] = sqrtf(ok ? ssq1 : ssq0);
    out_pos[ul * 3 + 0] = ok ? px + ox : px;
    out_pos[ul * 3 + 1] = ok ? py + oy : py;
    out_pos[ul * 3 + 2] = ok ? pz + oz : pz;
  }
}

extern "C" void kernel_launch(void* const* d_in, const int* in_sizes, int n_in,
                              void* d_out, int out_size, void* d_ws, size_t ws_size,
                              hipStream_t stream) {
  const float* field = (const float*)d_in[0];
  const float* pos   = (const float*)d_in[1];
  const float* sig   = (const float*)d_in[2];
  const float* offs  = (const float*)d_in[3];
  const float* W1    = (const float*)d_in[4];
  const float* b1    = (const float*)d_in[5];
  const float* W2    = (const float*)d_in[6];
  const float* b2    = (const float*)d_in[7];
  float* out_stab = (float*)d_out;
  float* out_pos  = out_stab + NU;

  char* ws = (char*)d_ws;
  // ws layout: [0, 4812208) padded bf16 field; frag-major weights; bf16 signatures
  unsigned short* fpad = (unsigned short*)ws;
  unsigned short* w1t  = (unsigned short*)(ws + 4812800);
  unsigned short* w2t  = (unsigned short*)(ws + 4878336);
  unsigned short* sigb = (unsigned short*)(ws + 4915200);
  const size_t need_sigb = 4915200ull + (size_t)NU * DD * 2ull;

  prep_field<<<(PG * PG * PG + 255) / 256, 256, 0, stream>>>(field, fpad);
  prep_w<<<24, 256, 0, stream>>>(W1, W2, w1t, w2t);

  if (ws_size >= need_sigb) {
    prep_sig<<<NU * DD / 8 / 256, 256, 0, stream>>>(sig, sigb);
    atu_main<true><<<NU / 128, 256, 0, stream>>>(pos, sig, sigb, offs, b1, b2, fpad,
                                                 (const short8*)w1t, (const short8*)w2t,
                                                 out_stab, out_pos);
  } else {
    atu_main<false><<<NU / 128, 256, 0, stream>>>(pos, sig, sigb, offs, b1, b2, fpad,
                                                  (const short8*)w1t, (const short8*)w2t,
                                                  out_stab, out_pos);
  }
}

// Round 5
// 318.996 us; speedup vs baseline: 3.7831x; 1.1418x over previous
//
#include <hip/hip_runtime.h>
#include <hip/hip_bf16.h>

#define NU 262144
#define GG 128
#define PG 134          // padded field side (128 + 2*3)
#define DD 128
#define NCELL 4096      // 16^3 cells of 8^3 voxels

typedef __attribute__((ext_vector_type(8))) short short8;   // 8 bf16 (4 VGPR) MFMA frag
typedef __attribute__((ext_vector_type(4))) short short4v;  // 4 bf16
typedef __attribute__((ext_vector_type(4))) float f32x4;
typedef __attribute__((ext_vector_type(4))) int int4v;

// fp32 -> bf16, round-to-nearest-even
__device__ __forceinline__ unsigned short f2b(float f) {
  union { float f; unsigned u; } v; v.f = f;
  unsigned r = v.u + 0x7fffu + ((v.u >> 16) & 1u);
  return (unsigned short)(r >> 16);
}
__device__ __forceinline__ float b2f(unsigned short b) {
  union { unsigned u; float f; } v; v.u = ((unsigned)b) << 16; return v.f;
}

__device__ __forceinline__ float fast_tanh(float x) {
  float ax = fabsf(x);
  float e  = __expf(ax + ax);
  float t  = 1.0f - __fdividef(2.0f, e + 1.0f);
  return copysignf(t, x);
}

// neighborhood offset -> flat delta in padded 134^3 field
struct alignas(16) DoffT { int v[128]; };
static constexpr DoffT mkdoff() {
  DoffT t{};
  for (int d = 0; d < 128; ++d) {
    int i = d / 49, r = d % 49, j = r / 7, k = r % 7;
    t.v[d] = ((i - 3) * PG + (j - 3)) * PG + (k - 3);
  }
  return t;
}
__device__ constexpr DoffT DOFF = mkdoff();

__device__ __forceinline__ int cell_of(float px, float py, float pz) {
  int cx = min(max((int)px, 0), GG - 1) >> 3;
  int cy = min(max((int)py, 0), GG - 1) >> 3;
  int cz = min(max((int)pz, 0), GG - 1) >> 3;
  return (cx << 8) | (cy << 4) | cz;
}

// ---------------- prep 1: clamped pad + bf16 convert of the field ----------------
__global__ void prep_field(const float* __restrict__ f, unsigned short* __restrict__ fp) {
  int idx = blockIdx.x * 256 + threadIdx.x;
  if (idx >= PG * PG * PG) return;
  int z = idx % PG, t = idx / PG;
  int y = t % PG, x = t / PG;
  int xx = min(max(x - 3, 0), GG - 1);
  int yy = min(max(y - 3, 0), GG - 1);
  int zz = min(max(z - 3, 0), GG - 1);
  fp[idx] = f2b(f[(xx * GG + yy) * GG + zz]);
}

// ---------------- prep 2: W1/W2 -> frag-major bf16 ----------------
__global__ void prep_w(const float* __restrict__ W1, const float* __restrict__ W2,
                       unsigned short* __restrict__ w1t, unsigned short* __restrict__ w2t) {
  int idx = blockIdx.x * 256 + threadIdx.x;   // one 16B frag-chunk per thread
  if (idx < 4096) {                            // W1: 8 kt * 8 nt * 64 lanes
    int kt = idx >> 9, nt = (idx >> 6) & 7, ln = idx & 63;
    int n = nt * 16 + (ln & 15), k0 = kt * 32 + (ln >> 4) * 8;
    short8 s;
#pragma unroll
    for (int j = 0; j < 8; ++j) s[j] = (short)f2b(W1[(k0 + j) * DD + n]);
    ((short8*)w1t)[idx] = s;
  } else if (idx < 6144) {                     // W2: 4 kt * 8 nt * 64 lanes
    int c = idx - 4096;
    int kt = c >> 9, nt = (c >> 6) & 7, ln = c & 63;
    int n = nt * 16 + (ln & 15), k0 = kt * 32 + (ln >> 4) * 8;
    short8 s;
#pragma unroll
    for (int j = 0; j < 8; ++j) s[j] = (short)f2b(W2[(k0 + j) * DD + n]);
    ((short8*)w2t)[c] = s;
  }
}

// ---------------- counting sort by cell ----------------
__global__ void zero_k(int* __restrict__ cursor) {
  int i = blockIdx.x * 256 + threadIdx.x;
  if (i < NCELL) cursor[i] = 0;
}
__global__ void hist_k(const float* __restrict__ pos, int* __restrict__ cursor) {
  int u = blockIdx.x * 256 + threadIdx.x;
  atomicAdd(&cursor[cell_of(pos[u * 3], pos[u * 3 + 1], pos[u * 3 + 2])], 1);
}
__global__ void scan_k(int* __restrict__ cursor) {   // 1 block, 256 threads, 4096 bins
  __shared__ int sums[256];
  int t = threadIdx.x;
  int local[16];
  int partial = 0;
#pragma unroll
  for (int j = 0; j < 16; ++j) { local[j] = cursor[t * 16 + j]; partial += local[j]; }
  sums[t] = partial;
  __syncthreads();
  for (int off = 1; off < 256; off <<= 1) {
    int v = (t >= off) ? sums[t - off] : 0;
    __syncthreads();
    sums[t] += v;
    __syncthreads();
  }
  int excl = sums[t] - partial;
#pragma unroll
  for (int j = 0; j < 16; ++j) { cursor[t * 16 + j] = excl; excl += local[j]; }
}
__global__ void scatter_k(const float* __restrict__ pos, int* __restrict__ cursor,
                          int* __restrict__ perm) {
  int u = blockIdx.x * 256 + threadIdx.x;
  int dst = atomicAdd(&cursor[cell_of(pos[u * 3], pos[u * 3 + 1], pos[u * 3 + 2])], 1);
  perm[dst] = u;
}

// ---------------- permute pos/offs and sig(->bf16) into sorted order ----------------
__global__ void permute_pv(const float* __restrict__ pos, const float* __restrict__ offs,
                           const int* __restrict__ perm,
                           float* __restrict__ posP, float* __restrict__ offsP) {
  int u = blockIdx.x * 256 + threadIdx.x;
  int o = perm[u];
#pragma unroll
  for (int j = 0; j < 3; ++j) {
    posP[u * 3 + j]  = pos[o * 3 + j];
    offsP[u * 3 + j] = offs[o * 3 + j];
  }
}
__global__ void permute_sig(const float* __restrict__ sig, const int* __restrict__ perm,
                            unsigned short* __restrict__ sigbP) {
  int i = blockIdx.x * 256 + threadIdx.x;     // NU*16 chunks of 8 elems
  int u = i >> 4, c = i & 15;
  int o = perm[u];
  const f32x4* p = (const f32x4*)(sig + o * DD + c * 8);
  f32x4 a = p[0], b = p[1];
  short8 v;
  v[0] = (short)f2b(a[0]); v[1] = (short)f2b(a[1]);
  v[2] = (short)f2b(a[2]); v[3] = (short)f2b(a[3]);
  v[4] = (short)f2b(b[0]); v[5] = (short)f2b(b[1]);
  v[6] = (short)f2b(b[2]); v[7] = (short)f2b(b[3]);
  *(short8*)(sigbP + u * DD + c * 8) = v;
}

// ---------------- plain sig->bf16 (fallback mode 1) ----------------
__global__ void prep_sig(const float* __restrict__ s, unsigned short* __restrict__ sb) {
  int i = (blockIdx.x * 256 + threadIdx.x) * 8;
  const f32x4* p = (const f32x4*)(s + i);
  f32x4 a = p[0], b = p[1];
  short8 o;
  o[0] = (short)f2b(a[0]); o[1] = (short)f2b(a[1]);
  o[2] = (short)f2b(a[2]); o[3] = (short)f2b(a[3]);
  o[4] = (short)f2b(b[0]); o[5] = (short)f2b(b[1]);
  o[6] = (short)f2b(b[2]); o[7] = (short)f2b(b[3]);
  *(short8*)(sb + i) = o;
}

// ---------------- main kernel: 4 waves * 32 units per block (128 units/block) ----------------
// MODE 2: sorted/permuted operands + scatter outputs via perm
// MODE 1: unsorted, bf16 signatures   MODE 0: unsorted, fp32 signatures
template<int MODE>
__global__ __launch_bounds__(256, 3) void atu_main(
    const float* __restrict__ pos, const float* __restrict__ sig,
    const unsigned short* __restrict__ sigb,
    const float* __restrict__ offs, const int* __restrict__ perm,
    const float* __restrict__ b1, const float* __restrict__ b2,
    const unsigned short* __restrict__ fpad,
    const short8* __restrict__ w1f, const short8* __restrict__ w2f,
    float* __restrict__ out_stab, float* __restrict__ out_pos)
{
  __shared__ unsigned short hs[4][4096];     // 8KB per wave, 32KB total
  const int tid  = threadIdx.x;
  const int wid  = tid >> 6, lane = tid & 63;
  const int lg   = lane >> 4, lm = lane & 15;
  const int ubase = blockIdx.x * 128 + wid * 32;
  char* hsb = (char*)&hs[wid][0];

  float ssq0, ssq1;

#pragma unroll 1
  for (int ev = 0; ev < 2; ++ev) {
    // ---- per-unit-tile gather bases (padded coords, no clamps needed later) ----
    int abase[2];
#pragma unroll
    for (int ut = 0; ut < 2; ++ut) {
      int u = ubase + ut * 16 + lm;
      float px = pos[u * 3 + 0], py = pos[u * 3 + 1], pz = pos[u * 3 + 2];
      if (ev) { px += offs[u * 3 + 0]; py += offs[u * 3 + 1]; pz += offs[u * 3 + 2]; }
      int pcx = min(max((int)px, 0), GG - 1);
      int pcy = min(max((int)py, 0), GG - 1);
      int pcz = min(max((int)pz, 0), GG - 1);
      abase[ut] = ((pcx + 3) * PG + (pcy + 3)) * PG + (pcz + 3);
    }

    // ---- GEMM1: hT[128 feat][32 units] += W1t x combinedT ----
    f32x4 acc[8][2];
#pragma unroll
    for (int nt = 0; nt < 8; ++nt)
#pragma unroll
      for (int ut = 0; ut < 2; ++ut) acc[nt][ut] = f32x4{0.f, 0.f, 0.f, 0.f};

#pragma unroll 1
    for (int kt = 0; kt < 4; ++kt) {          // signature half (k = 0..127)
      short8 bfr[2];
#pragma unroll
      for (int ut = 0; ut < 2; ++ut) {
        int u = ubase + ut * 16 + lm;
        if constexpr (MODE >= 1) {
          bfr[ut] = *(const short8*)(sigb + u * DD + kt * 32 + lg * 8);
        } else {
          const f32x4* sp = (const f32x4*)(sig + (u * DD + kt * 32 + lg * 8));
          f32x4 s0 = sp[0], s1 = sp[1];
          short8 fr;
          fr[0] = (short)f2b(s0[0]); fr[1] = (short)f2b(s0[1]);
          fr[2] = (short)f2b(s0[2]); fr[3] = (short)f2b(s0[3]);
          fr[4] = (short)f2b(s1[0]); fr[5] = (short)f2b(s1[1]);
          fr[6] = (short)f2b(s1[2]); fr[7] = (short)f2b(s1[3]);
          bfr[ut] = fr;
        }
      }
#pragma unroll
      for (int nt = 0; nt < 8; ++nt) {
        short8 af = w1f[(kt * 8 + nt) * 64 + lane];
#pragma unroll
        for (int ut = 0; ut < 2; ++ut)
          acc[nt][ut] = __builtin_amdgcn_mfma_f32_16x16x32_bf16(af, bfr[ut], acc[nt][ut], 0, 0, 0);
      }
    }

#pragma unroll 1
    for (int kt = 4; kt < 8; ++kt) {          // gathered-local half (k = 128..255)
      int d0 = (kt - 4) * 32 + lg * 8;
      int4v dv0 = *(const int4v*)&DOFF.v[d0];
      int4v dv1 = *(const int4v*)&DOFF.v[d0 + 4];
      short8 bfr[2];
#pragma unroll
      for (int ut = 0; ut < 2; ++ut) {
        int ab = abase[ut];
        short8 fr;
        fr[0] = (short)fpad[ab + dv0[0]]; fr[1] = (short)fpad[ab + dv0[1]];
        fr[2] = (short)fpad[ab + dv0[2]]; fr[3] = (short)fpad[ab + dv0[3]];
        fr[4] = (short)fpad[ab + dv1[0]]; fr[5] = (short)fpad[ab + dv1[1]];
        fr[6] = (short)fpad[ab + dv1[2]]; fr[7] = (short)fpad[ab + dv1[3]];
        bfr[ut] = fr;
      }
#pragma unroll
      for (int nt = 0; nt < 8; ++nt) {
        short8 af = w1f[(kt * 8 + nt) * 64 + lane];
#pragma unroll
        for (int ut = 0; ut < 2; ++ut)
          acc[nt][ut] = __builtin_amdgcn_mfma_f32_16x16x32_bf16(af, bfr[ut], acc[nt][ut], 0, 0, 0);
      }
    }

    // ---- bias + tanh + write h to swizzled per-wave LDS (transpose) ----
#pragma unroll
    for (int nt = 0; nt < 8; ++nt) {
      f32x4 b1v = *(const f32x4*)(b1 + nt * 16 + lg * 4);
#pragma unroll
      for (int ut = 0; ut < 2; ++ut) {
        int u = ut * 16 + lm;
        float h0 = fast_tanh(acc[nt][ut][0] + b1v[0]);
        float h1 = fast_tanh(acc[nt][ut][1] + b1v[1]);
        float h2 = fast_tanh(acc[nt][ut][2] + b1v[2]);
        float h3 = fast_tanh(acc[nt][ut][3] + b1v[3]);
        unsigned q0 = (unsigned)f2b(h0) | ((unsigned)f2b(h1) << 16);
        unsigned q1 = (unsigned)f2b(h2) | ((unsigned)f2b(h3) << 16);
        int byte = (u * 256 + nt * 32 + lg * 8) ^ ((u & 7) << 4);
        *(unsigned long long*)(hsb + byte) =
            (unsigned long long)q0 | ((unsigned long long)q1 << 32);
      }
    }

    // ---- GEMM2 in two nt-halves (32-reg accumulator each) + fused norm ----
    float ssq[2] = {0.f, 0.f};
#pragma unroll 1
    for (int half = 0; half < 2; ++half) {
      f32x4 acc2[4][2];
#pragma unroll
      for (int n2 = 0; n2 < 4; ++n2)
#pragma unroll
        for (int ut = 0; ut < 2; ++ut) acc2[n2][ut] = f32x4{0.f, 0.f, 0.f, 0.f};

#pragma unroll 1
      for (int kt = 0; kt < 4; ++kt) {
        short8 hfr[2];
#pragma unroll
        for (int ut = 0; ut < 2; ++ut) {
          int u = ut * 16 + lm;
          int byte = (u * 256 + kt * 64 + lg * 16) ^ ((u & 7) << 4);
          hfr[ut] = *(const short8*)(hsb + byte);
        }
#pragma unroll
        for (int n2 = 0; n2 < 4; ++n2) {
          int nt = half * 4 + n2;
          short8 af = w2f[(kt * 8 + nt) * 64 + lane];
#pragma unroll
          for (int ut = 0; ut < 2; ++ut)
            acc2[n2][ut] = __builtin_amdgcn_mfma_f32_16x16x32_bf16(af, hfr[ut], acc2[n2][ut], 0, 0, 0);
        }
      }

#pragma unroll
      for (int n2 = 0; n2 < 4; ++n2) {
        int nt = half * 4 + n2;
        f32x4 b2v = *(const f32x4*)(b2 + nt * 16 + lg * 4);
#pragma unroll
        for (int ut = 0; ut < 2; ++ut) {
          int u = ubase + ut * 16 + lm;
          float sv0, sv1, sv2, sv3;
          if constexpr (MODE >= 1) {
            short4v hv = *(const short4v*)(sigb + u * DD + nt * 16 + lg * 4);
            sv0 = b2f((unsigned short)hv[0]); sv1 = b2f((unsigned short)hv[1]);
            sv2 = b2f((unsigned short)hv[2]); sv3 = b2f((unsigned short)hv[3]);
          } else {
            f32x4 sv = *(const f32x4*)(sig + (u * DD + nt * 16 + lg * 4));
            sv0 = sv[0]; sv1 = sv[1]; sv2 = sv[2]; sv3 = sv[3];
          }
          float d0 = acc2[n2][ut][0] + b2v[0] - sv0;
          float d1 = acc2[n2][ut][1] + b2v[1] - sv1;
          float d2 = acc2[n2][ut][2] + b2v[2] - sv2;
          float d3 = acc2[n2][ut][3] + b2v[3] - sv3;
          ssq[ut] = fmaf(d0, d0, ssq[ut]);
          ssq[ut] = fmaf(d1, d1, ssq[ut]);
          ssq[ut] = fmaf(d2, d2, ssq[ut]);
          ssq[ut] = fmaf(d3, d3, ssq[ut]);
        }
      }
    }

#pragma unroll
    for (int ut = 0; ut < 2; ++ut) {
      ssq[ut] += __shfl_xor(ssq[ut], 16, 64);
      ssq[ut] += __shfl_xor(ssq[ut], 32, 64);
    }
    float r = (lane & 16) ? ssq[1] : ssq[0];
    if (ev == 0) ssq0 = r; else ssq1 = r;
  }

  // ---- accept / outputs: lane l (<32) owns unit ubase + l; scatter via perm in MODE 2 ----
  if (lane < 32) {
    int ul = ubase + lane;
    float px = pos[ul * 3 + 0], py = pos[ul * 3 + 1], pz = pos[ul * 3 + 2];
    float ox = offs[ul * 3 + 0], oy = offs[ul * 3 + 1], oz = offs[ul * 3 + 2];
    bool ok = ssq1 <= ssq0;
    int pu = (MODE == 2) ? perm[ul] : ul;
    out_stab[pu] = sqrtf(ok ? ssq1 : ssq0);
    out_pos[pu * 3 + 0] = ok ? px + ox : px;
    out_pos[pu * 3 + 1] = ok ? py + oy : py;
    out_pos[pu * 3 + 2] = ok ? pz + oz : pz;
  }
}

extern "C" void kernel_launch(void* const* d_in, const int* in_sizes, int n_in,
                              void* d_out, int out_size, void* d_ws, size_t ws_size,
                              hipStream_t stream) {
  const float* field = (const float*)d_in[0];
  const float* pos   = (const float*)d_in[1];
  const float* sig   = (const float*)d_in[2];
  const float* offs  = (const float*)d_in[3];
  const float* W1    = (const float*)d_in[4];
  const float* b1    = (const float*)d_in[5];
  const float* W2    = (const float*)d_in[6];
  const float* b2    = (const float*)d_in[7];
  float* out_stab = (float*)d_out;
  float* out_pos  = out_stab + NU;

  char* ws = (char*)d_ws;
  // ws layout
  unsigned short* fpad  = (unsigned short*)ws;                    // 4,812,208 B
  unsigned short* w1t   = (unsigned short*)(ws + 4812800);        // 65,536 B
  unsigned short* w2t   = (unsigned short*)(ws + 4878336);        // 32,768 B
  unsigned short* sigbP = (unsigned short*)(ws + 4915200);        // 67,108,864 B
  float*          posP  = (float*)(ws + 72024064);                // 3,145,728 B
  float*          offsP = (float*)(ws + 75169792);                // 3,145,728 B
  int*            perm  = (int*)(ws + 78315520);                  // 1,048,576 B
  int*            cursor= (int*)(ws + 79364096);                  // 16,384 B
  const size_t need2 = 79380480ull;
  const size_t need1 = 72024064ull;

  prep_field<<<(PG * PG * PG + 255) / 256, 256, 0, stream>>>(field, fpad);
  prep_w<<<24, 256, 0, stream>>>(W1, W2, w1t, w2t);

  if (ws_size >= need2) {
    zero_k<<<NCELL / 256, 256, 0, stream>>>(cursor);
    hist_k<<<NU / 256, 256, 0, stream>>>(pos, cursor);
    scan_k<<<1, 256, 0, stream>>>(cursor);
    scatter_k<<<NU / 256, 256, 0, stream>>>(pos, cursor, perm);
    permute_pv<<<NU / 256, 256, 0, stream>>>(pos, offs, perm, posP, offsP);
    permute_sig<<<NU * 16 / 256, 256, 0, stream>>>(sig, perm, sigbP);
    atu_main<2><<<NU / 128, 256, 0, stream>>>(posP, sig, sigbP, offsP, perm, b1, b2, fpad,
                                              (const short8*)w1t, (const short8*)w2t,
                                              out_stab, out_pos);
  } else if (ws_size >= need1) {
    prep_sig<<<NU * DD / 8 / 256, 256, 0, stream>>>(sig, sigbP);
    atu_main<1><<<NU / 128, 256, 0, stream>>>(pos, sig, sigbP, offs, nullptr, b1, b2, fpad,
                                              (const short8*)w1t, (const short8*)w2t,
                                              out_stab, out_pos);
  } else {
    atu_main<0><<<NU / 128, 256, 0, stream>>>(pos, sig, nullptr, offs, nullptr, b1, b2, fpad,
                                              (const short8*)w1t, (const short8*)w2t,
                                              out_stab, out_pos);
  }
}

// Round 6
// 310.880 us; speedup vs baseline: 3.8818x; 1.0261x over previous
//
#include <hip/hip_runtime.h>
#include <hip/hip_bf16.h>

#define NU 262144
#define GG 128
#define PG 134          // padded field side (128 + 2*3)
#define DD 128
#define NCELL 4096      // 16^3 cells of 8^3 voxels

typedef __attribute__((ext_vector_type(8))) short short8;   // 8 bf16 (4 VGPR) MFMA frag
typedef __attribute__((ext_vector_type(4))) short short4v;  // 4 bf16
typedef __attribute__((ext_vector_type(4))) float f32x4;

// fp32 -> bf16, round-to-nearest-even
__device__ __forceinline__ unsigned short f2b(float f) {
  union { float f; unsigned u; } v; v.f = f;
  unsigned r = v.u + 0x7fffu + ((v.u >> 16) & 1u);
  return (unsigned short)(r >> 16);
}
__device__ __forceinline__ float b2f(unsigned short b) {
  union { unsigned u; float f; } v; v.u = ((unsigned)b) << 16; return v.f;
}

__device__ __forceinline__ float fast_tanh(float x) {
  float ax = fabsf(x);
  float e  = __expf(ax + ax);
  float t  = 1.0f - __fdividef(2.0f, e + 1.0f);
  return copysignf(t, x);
}

// Row table: the 128 neighborhood offsets = 18 full z-rows of 7 + one 2-elem stub.
// Row r (r<18): di=-3+r/7, dj=-3+r%7, z from -3.  r=18 (and dead row 19): di=-1,dj=1.
// rowdelta = flat delta of the row's first voxel (k=-3) in the padded field.
struct alignas(16) RowdT { int v[20]; };
static constexpr RowdT mkrowd() {
  RowdT t{};
  for (int r = 0; r < 20; ++r) {
    int rr = (r < 18) ? r : 18;
    int di = (rr < 18) ? (-3 + rr / 7) : -1;
    int dj = (rr < 18) ? (-3 + rr % 7) : 1;
    t.v[r] = (di * PG + dj) * PG - 3;
  }
  return t;
}
__device__ constexpr RowdT ROWD = mkrowd();

__device__ __forceinline__ int cell_of(float px, float py, float pz) {
  int cx = min(max((int)px, 0), GG - 1) >> 3;
  int cy = min(max((int)py, 0), GG - 1) >> 3;
  int cz = min(max((int)pz, 0), GG - 1) >> 3;
  return (cx << 8) | (cy << 4) | cz;
}

// ---------------- prep 1: clamped pad + bf16 convert of the field ----------------
__global__ void prep_field(const float* __restrict__ f, unsigned short* __restrict__ fp) {
  int idx = blockIdx.x * 256 + threadIdx.x;
  if (idx >= PG * PG * PG) return;
  int z = idx % PG, t = idx / PG;
  int y = t % PG, x = t / PG;
  int xx = min(max(x - 3, 0), GG - 1);
  int yy = min(max(y - 3, 0), GG - 1);
  int zz = min(max(z - 3, 0), GG - 1);
  fp[idx] = f2b(f[(xx * GG + yy) * GG + zz]);
}

// ---------------- prep 2: W1/W2 -> frag-major bf16 (W1 gather half k-reordered) ----
// w1f: 9 kt (4 sig + 5 gather-row kts). Gather slot s=(kt-4)*32+lg*8+j -> row r=s/8,
// weight = W1[128 + (r<18 ? r*7+j : 126+j)][n] if (r<18&&j<7)||(r==18&&j<2) else 0.
__global__ void prep_w(const float* __restrict__ W1, const float* __restrict__ W2,
                       unsigned short* __restrict__ w1t, unsigned short* __restrict__ w2t) {
  int idx = blockIdx.x * 256 + threadIdx.x;
  if (idx < 4608) {                            // W1: 9 kt * 8 nt * 64 lanes
    int kt = idx >> 9, nt = (idx >> 6) & 7, ln = idx & 63;
    int n = nt * 16 + (ln & 15);
    short8 s;
    if (kt < 4) {
      int k0 = kt * 32 + (ln >> 4) * 8;
#pragma unroll
      for (int j = 0; j < 8; ++j) s[j] = (short)f2b(W1[(k0 + j) * DD + n]);
    } else {
      int r = (kt - 4) * 4 + (ln >> 4);        // 0..19
#pragma unroll
      for (int j = 0; j < 8; ++j) {
        bool valid = (r < 18 && j < 7) || (r == 18 && j < 2);
        int row = 128 + ((r < 18) ? (r * 7 + j) : (126 + j));
        s[j] = valid ? (short)f2b(W1[row * DD + n]) : (short)0;
      }
    }
    ((short8*)w1t)[idx] = s;
  } else if (idx < 6656) {                     // W2: 4 kt * 8 nt * 64 lanes
    int c = idx - 4608;
    int kt = c >> 9, nt = (c >> 6) & 7, ln = c & 63;
    int n = nt * 16 + (ln & 15), k0 = kt * 32 + (ln >> 4) * 8;
    short8 s;
#pragma unroll
    for (int j = 0; j < 8; ++j) s[j] = (short)f2b(W2[(k0 + j) * DD + n]);
    ((short8*)w2t)[c] = s;
  }
}

// ---------------- counting sort by cell ----------------
__global__ void zero_k(int* __restrict__ cursor) {
  int i = blockIdx.x * 256 + threadIdx.x;
  if (i < NCELL) cursor[i] = 0;
}
__global__ void hist_k(const float* __restrict__ pos, int* __restrict__ cursor) {
  int u = blockIdx.x * 256 + threadIdx.x;
  atomicAdd(&cursor[cell_of(pos[u * 3], pos[u * 3 + 1], pos[u * 3 + 2])], 1);
}
__global__ void scan_k(int* __restrict__ cursor) {   // 1 block, 256 threads, 4096 bins
  __shared__ int sums[256];
  int t = threadIdx.x;
  int local[16];
  int partial = 0;
#pragma unroll
  for (int j = 0; j < 16; ++j) { local[j] = cursor[t * 16 + j]; partial += local[j]; }
  sums[t] = partial;
  __syncthreads();
  for (int off = 1; off < 256; off <<= 1) {
    int v = (t >= off) ? sums[t - off] : 0;
    __syncthreads();
    sums[t] += v;
    __syncthreads();
  }
  int excl = sums[t] - partial;
#pragma unroll
  for (int j = 0; j < 16; ++j) { cursor[t * 16 + j] = excl; excl += local[j]; }
}
__global__ void scatter_k(const float* __restrict__ pos, int* __restrict__ cursor,
                          int* __restrict__ perm) {
  int u = blockIdx.x * 256 + threadIdx.x;
  int dst = atomicAdd(&cursor[cell_of(pos[u * 3], pos[u * 3 + 1], pos[u * 3 + 2])], 1);
  perm[dst] = u;
}

// ---------------- permute pos/offs and sig(->bf16) into sorted order ----------------
__global__ void permute_pv(const float* __restrict__ pos, const float* __restrict__ offs,
                           const int* __restrict__ perm,
                           float* __restrict__ posP, float* __restrict__ offsP) {
  int u = blockIdx.x * 256 + threadIdx.x;
  int o = perm[u];
#pragma unroll
  for (int j = 0; j < 3; ++j) {
    posP[u * 3 + j]  = pos[o * 3 + j];
    offsP[u * 3 + j] = offs[o * 3 + j];
  }
}
__global__ void permute_sig(const float* __restrict__ sig, const int* __restrict__ perm,
                            unsigned short* __restrict__ sigbP) {
  int i = blockIdx.x * 256 + threadIdx.x;     // NU*16 chunks of 8 elems
  int u = i >> 4, c = i & 15;
  int o = perm[u];
  const f32x4* p = (const f32x4*)(sig + o * DD + c * 8);
  f32x4 a = p[0], b = p[1];
  short8 v;
  v[0] = (short)f2b(a[0]); v[1] = (short)f2b(a[1]);
  v[2] = (short)f2b(a[2]); v[3] = (short)f2b(a[3]);
  v[4] = (short)f2b(b[0]); v[5] = (short)f2b(b[1]);
  v[6] = (short)f2b(b[2]); v[7] = (short)f2b(b[3]);
  *(short8*)(sigbP + u * DD + c * 8) = v;
}

// ---------------- plain sig->bf16 (fallback mode 1) ----------------
__global__ void prep_sig(const float* __restrict__ s, unsigned short* __restrict__ sb) {
  int i = (blockIdx.x * 256 + threadIdx.x) * 8;
  const f32x4* p = (const f32x4*)(s + i);
  f32x4 a = p[0], b = p[1];
  short8 o;
  o[0] = (short)f2b(a[0]); o[1] = (short)f2b(a[1]);
  o[2] = (short)f2b(a[2]); o[3] = (short)f2b(a[3]);
  o[4] = (short)f2b(b[0]); o[5] = (short)f2b(b[1]);
  o[6] = (short)f2b(b[2]); o[7] = (short)f2b(b[3]);
  *(short8*)(sb + i) = o;
}

// ---------------- main kernel: 4 waves * 64 units per block (256 units/block) ----------------
// launch_bounds(256,2): 256-VGPR tier (acc[8][4]=128 + transients ~ 180, no spill).
// MODE 2: sorted/permuted operands + scatter outputs via perm
// MODE 1: unsorted, bf16 signatures   MODE 0: unsorted, fp32 signatures
template<int MODE>
__global__ __launch_bounds__(256, 2) void atu_main(
    const float* __restrict__ pos, const float* __restrict__ sig,
    const unsigned short* __restrict__ sigb,
    const float* __restrict__ offs, const int* __restrict__ perm,
    const float* __restrict__ b1, const float* __restrict__ b2,
    const unsigned short* __restrict__ fpad,
    const short8* __restrict__ w1f, const short8* __restrict__ w2f,
    float* __restrict__ out_stab, float* __restrict__ out_pos)
{
  __shared__ unsigned short hs[4][8192];     // 16KB per wave, 64KB total
  const int tid  = threadIdx.x;
  const int wid  = tid >> 6, lane = tid & 63;
  const int lg   = lane >> 4, lm = lane & 15;
  const int ubase = blockIdx.x * 256 + wid * 64;
  char* hsb = (char*)&hs[wid][0];
  const char* fpadb = (const char*)fpad;

  float ssq0, ssq1;

#pragma unroll 1
  for (int ev = 0; ev < 2; ++ev) {
    // ---- per-unit-tile gather bases (padded coords) ----
    int abase[4];
#pragma unroll
    for (int ut = 0; ut < 4; ++ut) {
      int u = ubase + ut * 16 + lm;
      float px = pos[u * 3 + 0], py = pos[u * 3 + 1], pz = pos[u * 3 + 2];
      if (ev) { px += offs[u * 3 + 0]; py += offs[u * 3 + 1]; pz += offs[u * 3 + 2]; }
      int pcx = min(max((int)px, 0), GG - 1);
      int pcy = min(max((int)py, 0), GG - 1);
      int pcz = min(max((int)pz, 0), GG - 1);
      abase[ut] = ((pcx + 3) * PG + (pcy + 3)) * PG + (pcz + 3);
    }

    // ---- GEMM1: hT[128 feat][64 units] += W1t x combinedT (9 kt: 4 sig + 5 row) ----
    f32x4 acc[8][4];
#pragma unroll
    for (int nt = 0; nt < 8; ++nt)
#pragma unroll
      for (int ut = 0; ut < 4; ++ut) acc[nt][ut] = f32x4{0.f, 0.f, 0.f, 0.f};

#pragma unroll 1
    for (int kt = 0; kt < 4; ++kt) {          // signature half (k = 0..127)
      short8 bfr[4];
#pragma unroll
      for (int ut = 0; ut < 4; ++ut) {
        int u = ubase + ut * 16 + lm;
        if constexpr (MODE >= 1) {
          bfr[ut] = *(const short8*)(sigb + u * DD + kt * 32 + lg * 8);
        } else {
          const f32x4* sp = (const f32x4*)(sig + (u * DD + kt * 32 + lg * 8));
          f32x4 s0 = sp[0], s1 = sp[1];
          short8 fr;
          fr[0] = (short)f2b(s0[0]); fr[1] = (short)f2b(s0[1]);
          fr[2] = (short)f2b(s0[2]); fr[3] = (short)f2b(s0[3]);
          fr[4] = (short)f2b(s1[0]); fr[5] = (short)f2b(s1[1]);
          fr[6] = (short)f2b(s1[2]); fr[7] = (short)f2b(s1[3]);
          bfr[ut] = fr;
        }
      }
#pragma unroll
      for (int nt = 0; nt < 8; ++nt) {
        short8 af = w1f[(kt * 8 + nt) * 64 + lane];
#pragma unroll
        for (int ut = 0; ut < 4; ++ut)
          acc[nt][ut] = __builtin_amdgcn_mfma_f32_16x16x32_bf16(af, bfr[ut], acc[nt][ut], 0, 0, 0);
      }
    }

#pragma unroll 1
    for (int kt = 4; kt < 9; ++kt) {          // gathered half: one 8-voxel z-row per frag
      int rd = ROWD.v[(kt - 4) * 4 + lg];
      short8 bfr[4];
#pragma unroll
      for (int ut = 0; ut < 4; ++ut)
        bfr[ut] = *(const short8*)(fpadb + 2 * (abase[ut] + rd));   // 2B-aligned 16B load
#pragma unroll
      for (int nt = 0; nt < 8; ++nt) {
        short8 af = w1f[(kt * 8 + nt) * 64 + lane];
#pragma unroll
        for (int ut = 0; ut < 4; ++ut)
          acc[nt][ut] = __builtin_amdgcn_mfma_f32_16x16x32_bf16(af, bfr[ut], acc[nt][ut], 0, 0, 0);
      }
    }

    // ---- bias + tanh + write h to swizzled per-wave LDS (transpose) ----
#pragma unroll
    for (int nt = 0; nt < 8; ++nt) {
      f32x4 b1v = *(const f32x4*)(b1 + nt * 16 + lg * 4);
#pragma unroll
      for (int ut = 0; ut < 4; ++ut) {
        int u = ut * 16 + lm;
        float h0 = fast_tanh(acc[nt][ut][0] + b1v[0]);
        float h1 = fast_tanh(acc[nt][ut][1] + b1v[1]);
        float h2 = fast_tanh(acc[nt][ut][2] + b1v[2]);
        float h3 = fast_tanh(acc[nt][ut][3] + b1v[3]);
        unsigned q0 = (unsigned)f2b(h0) | ((unsigned)f2b(h1) << 16);
        unsigned q1 = (unsigned)f2b(h2) | ((unsigned)f2b(h3) << 16);
        int byte = (u * 256 + nt * 32 + lg * 8) ^ ((u & 7) << 4);
        *(unsigned long long*)(hsb + byte) =
            (unsigned long long)q0 | ((unsigned long long)q1 << 32);
      }
    }

    // ---- GEMM2 in two nt-halves (64-reg accumulator each) + fused norm ----
    float ssq[4] = {0.f, 0.f, 0.f, 0.f};
#pragma unroll 1
    for (int half = 0; half < 2; ++half) {
      f32x4 acc2[4][4];
#pragma unroll
      for (int n2 = 0; n2 < 4; ++n2)
#pragma unroll
        for (int ut = 0; ut < 4; ++ut) acc2[n2][ut] = f32x4{0.f, 0.f, 0.f, 0.f};

#pragma unroll 1
      for (int kt = 0; kt < 4; ++kt) {
        short8 hfr[4];
#pragma unroll
        for (int ut = 0; ut < 4; ++ut) {
          int u = ut * 16 + lm;
          int byte = (u * 256 + kt * 64 + lg * 16) ^ ((u & 7) << 4);
          hfr[ut] = *(const short8*)(hsb + byte);
        }
#pragma unroll
        for (int n2 = 0; n2 < 4; ++n2) {
          int nt = half * 4 + n2;
          short8 af = w2f[(kt * 8 + nt) * 64 + lane];
#pragma unroll
          for (int ut = 0; ut < 4; ++ut)
            acc2[n2][ut] = __builtin_amdgcn_mfma_f32_16x16x32_bf16(af, hfr[ut], acc2[n2][ut], 0, 0, 0);
        }
      }

#pragma unroll
      for (int n2 = 0; n2 < 4; ++n2) {
        int nt = half * 4 + n2;
        f32x4 b2v = *(const f32x4*)(b2 + nt * 16 + lg * 4);
#pragma unroll
        for (int ut = 0; ut < 4; ++ut) {
          int u = ubase + ut * 16 + lm;
          float sv0, sv1, sv2, sv3;
          if constexpr (MODE >= 1) {
            short4v hv = *(const short4v*)(sigb + u * DD + nt * 16 + lg * 4);
            sv0 = b2f((unsigned short)hv[0]); sv1 = b2f((unsigned short)hv[1]);
            sv2 = b2f((unsigned short)hv[2]); sv3 = b2f((unsigned short)hv[3]);
          } else {
            f32x4 sv = *(const f32x4*)(sig + (u * DD + nt * 16 + lg * 4));
            sv0 = sv[0]; sv1 = sv[1]; sv2 = sv[2]; sv3 = sv[3];
          }
          float d0 = acc2[n2][ut][0] + b2v[0] - sv0;
          float d1 = acc2[n2][ut][1] + b2v[1] - sv1;
          float d2 = acc2[n2][ut][2] + b2v[2] - sv2;
          float d3 = acc2[n2][ut][3] + b2v[3] - sv3;
          ssq[ut] = fmaf(d0, d0, ssq[ut]);
          ssq[ut] = fmaf(d1, d1, ssq[ut]);
          ssq[ut] = fmaf(d2, d2, ssq[ut]);
          ssq[ut] = fmaf(d3, d3, ssq[ut]);
        }
      }
    }

#pragma unroll
    for (int ut = 0; ut < 4; ++ut) {
      ssq[ut] += __shfl_xor(ssq[ut], 16, 64);
      ssq[ut] += __shfl_xor(ssq[ut], 32, 64);
    }
    float r = (lg == 0) ? ssq[0] : (lg == 1) ? ssq[1] : (lg == 2) ? ssq[2] : ssq[3];
    if (ev == 0) ssq0 = r; else ssq1 = r;
  }

  // ---- accept / outputs: lane l owns unit ubase + l; scatter via perm in MODE 2 ----
  {
    int ul = ubase + lane;
    float px = pos[ul * 3 + 0], py = pos[ul * 3 + 1], pz = pos[ul * 3 + 2];
    float ox = offs[ul * 3 + 0], oy = offs[ul * 3 + 1], oz = offs[ul * 3 + 2];
    bool ok = ssq1 <= ssq0;
    int pu = (MODE == 2) ? perm[ul] : ul;
    out_stab[pu] = sqrtf(ok ? ssq1 : ssq0);
    out_pos[pu * 3 + 0] = ok ? px + ox : px;
    out_pos[pu * 3 + 1] = ok ? py + oy : py;
    out_pos[pu * 3 + 2] = ok ? pz + oz : pz;
  }
}

extern "C" void kernel_launch(void* const* d_in, const int* in_sizes, int n_in,
                              void* d_out, int out_size, void* d_ws, size_t ws_size,
                              hipStream_t stream) {
  const float* field = (const float*)d_in[0];
  const float* pos   = (const float*)d_in[1];
  const float* sig   = (const float*)d_in[2];
  const float* offs  = (const float*)d_in[3];
  const float* W1    = (const float*)d_in[4];
  const float* b1    = (const float*)d_in[5];
  const float* W2    = (const float*)d_in[6];
  const float* b2    = (const float*)d_in[7];
  float* out_stab = (float*)d_out;
  float* out_pos  = out_stab + NU;

  char* ws = (char*)d_ws;
  // ws layout
  unsigned short* fpad  = (unsigned short*)ws;                    // 4,812,208 B (+slack)
  unsigned short* w1t   = (unsigned short*)(ws + 4812800);        // 73,728 B (9 kt)
  unsigned short* w2t   = (unsigned short*)(ws + 4886528);        // 32,768 B
  unsigned short* sigbP = (unsigned short*)(ws + 4919296);        // 67,108,864 B
  float*          posP  = (float*)(ws + 72028160);                // 3,145,728 B
  float*          offsP = (float*)(ws + 75173888);                // 3,145,728 B
  int*            perm  = (int*)(ws + 78319616);                  // 1,048,576 B
  int*            cursor= (int*)(ws + 79368192);                  // 16,384 B
  const size_t need2 = 79384576ull;
  const size_t need1 = 72028160ull;

  prep_field<<<(PG * PG * PG + 255) / 256, 256, 0, stream>>>(field, fpad);
  prep_w<<<26, 256, 0, stream>>>(W1, W2, w1t, w2t);

  if (ws_size >= need2) {
    zero_k<<<NCELL / 256, 256, 0, stream>>>(cursor);
    hist_k<<<NU / 256, 256, 0, stream>>>(pos, cursor);
    scan_k<<<1, 256, 0, stream>>>(cursor);
    scatter_k<<<NU / 256, 256, 0, stream>>>(pos, cursor, perm);
    permute_pv<<<NU / 256, 256, 0, stream>>>(pos, offs, perm, posP, offsP);
    permute_sig<<<NU * 16 / 256, 256, 0, stream>>>(sig, perm, sigbP);
    atu_main<2><<<NU / 256, 256, 0, stream>>>(posP, sig, sigbP, offsP, perm, b1, b2, fpad,
                                              (const short8*)w1t, (const short8*)w2t,
                                              out_stab, out_pos);
  } else if (ws_size >= need1) {
    prep_sig<<<NU * DD / 8 / 256, 256, 0, stream>>>(sig, sigbP);
    atu_main<1><<<NU / 256, 256, 0, stream>>>(pos, sig, sigbP, offs, nullptr, b1, b2, fpad,
                                              (const short8*)w1t, (const short8*)w2t,
                                              out_stab, out_pos);
  } else {
    atu_main<0><<<NU / 256, 256, 0, stream>>>(pos, sig, nullptr, offs, nullptr, b1, b2, fpad,
                                              (const short8*)w1t, (const short8*)w2t,
                                              out_stab, out_pos);
  }
}

// Round 7
// 238.523 us; speedup vs baseline: 5.0594x; 1.3034x over previous
//
#include <hip/hip_runtime.h>
#include <hip/hip_bf16.h>

#define NU 262144
#define GG 128
#define PG 134          // padded field side (128 + 2*3)
#define DD 128
#define NCELL 4096      // 16^3 cells of 8^3 voxels

typedef __attribute__((ext_vector_type(8))) short short8;   // 8 bf16 (4 VGPR) MFMA frag
typedef __attribute__((ext_vector_type(4))) short short4v;  // 4 bf16
typedef __attribute__((ext_vector_type(4))) float f32x4;

// fp32 -> bf16, round-to-nearest-even
__device__ __forceinline__ unsigned short f2b(float f) {
  union { float f; unsigned u; } v; v.f = f;
  unsigned r = v.u + 0x7fffu + ((v.u >> 16) & 1u);
  return (unsigned short)(r >> 16);
}
__device__ __forceinline__ float b2f(unsigned short b) {
  union { unsigned u; float f; } v; v.u = ((unsigned)b) << 16; return v.f;
}

__device__ __forceinline__ float fast_tanh(float x) {
  float ax = fabsf(x);
  float e  = __expf(ax + ax);
  float t  = 1.0f - __fdividef(2.0f, e + 1.0f);
  return copysignf(t, x);
}

// Row table: 128 neighborhood offsets = 18 full z-rows of 7 + one 2-elem stub (+1 dead row).
struct alignas(16) RowdT { int v[20]; };
static constexpr RowdT mkrowd() {
  RowdT t{};
  for (int r = 0; r < 20; ++r) {
    int rr = (r < 18) ? r : 18;
    int di = (rr < 18) ? (-3 + rr / 7) : -1;
    int dj = (rr < 18) ? (-3 + rr % 7) : 1;
    t.v[r] = (di * PG + dj) * PG - 3;
  }
  return t;
}
__device__ constexpr RowdT ROWD = mkrowd();

__device__ __forceinline__ int cell_of(float px, float py, float pz) {
  int cx = min(max((int)px, 0), GG - 1) >> 3;
  int cy = min(max((int)py, 0), GG - 1) >> 3;
  int cz = min(max((int)pz, 0), GG - 1) >> 3;
  return (cx << 8) | (cy << 4) | cz;
}

// ---------------- prep 1: clamped pad + bf16 convert of the field ----------------
__global__ void prep_field(const float* __restrict__ f, unsigned short* __restrict__ fp) {
  int idx = blockIdx.x * 256 + threadIdx.x;
  if (idx >= PG * PG * PG) return;
  int z = idx % PG, t = idx / PG;
  int y = t % PG, x = t / PG;
  int xx = min(max(x - 3, 0), GG - 1);
  int yy = min(max(y - 3, 0), GG - 1);
  int zz = min(max(z - 3, 0), GG - 1);
  fp[idx] = f2b(f[(xx * GG + yy) * GG + zz]);
}

// ---------------- prep 2: W1/W2 -> frag-major bf16 (W1 gather half row-reordered) ----
__global__ void prep_w(const float* __restrict__ W1, const float* __restrict__ W2,
                       unsigned short* __restrict__ w1t, unsigned short* __restrict__ w2t) {
  int idx = blockIdx.x * 256 + threadIdx.x;
  if (idx < 4608) {                            // W1: 9 kt * 8 nt * 64 lanes
    int kt = idx >> 9, nt = (idx >> 6) & 7, ln = idx & 63;
    int n = nt * 16 + (ln & 15);
    short8 s;
    if (kt < 4) {
      int k0 = kt * 32 + (ln >> 4) * 8;
#pragma unroll
      for (int j = 0; j < 8; ++j) s[j] = (short)f2b(W1[(k0 + j) * DD + n]);
    } else {
      int r = (kt - 4) * 4 + (ln >> 4);        // 0..19
#pragma unroll
      for (int j = 0; j < 8; ++j) {
        bool valid = (r < 18 && j < 7) || (r == 18 && j < 2);
        int row = 128 + ((r < 18) ? (r * 7 + j) : (126 + j));
        s[j] = valid ? (short)f2b(W1[row * DD + n]) : (short)0;
      }
    }
    ((short8*)w1t)[idx] = s;
  } else if (idx < 6656) {                     // W2: 4 kt * 8 nt * 64 lanes
    int c = idx - 4608;
    int kt = c >> 9, nt = (c >> 6) & 7, ln = c & 63;
    int n = nt * 16 + (ln & 15), k0 = kt * 32 + (ln >> 4) * 8;
    short8 s;
#pragma unroll
    for (int j = 0; j < 8; ++j) s[j] = (short)f2b(W2[(k0 + j) * DD + n]);
    ((short8*)w2t)[c] = s;
  }
}

// ---------------- counting sort by cell ----------------
__global__ void zero_k(int* __restrict__ cursor) {
  int i = blockIdx.x * 256 + threadIdx.x;
  if (i < NCELL) cursor[i] = 0;
}
__global__ void hist_k(const float* __restrict__ pos, int* __restrict__ cursor) {
  int u = blockIdx.x * 256 + threadIdx.x;
  atomicAdd(&cursor[cell_of(pos[u * 3], pos[u * 3 + 1], pos[u * 3 + 2])], 1);
}
__global__ void scan_k(int* __restrict__ cursor) {   // 1 block, 256 threads, 4096 bins
  __shared__ int sums[256];
  int t = threadIdx.x;
  int local[16];
  int partial = 0;
#pragma unroll
  for (int j = 0; j < 16; ++j) { local[j] = cursor[t * 16 + j]; partial += local[j]; }
  sums[t] = partial;
  __syncthreads();
  for (int off = 1; off < 256; off <<= 1) {
    int v = (t >= off) ? sums[t - off] : 0;
    __syncthreads();
    sums[t] += v;
    __syncthreads();
  }
  int excl = sums[t] - partial;
#pragma unroll
  for (int j = 0; j < 16; ++j) { cursor[t * 16 + j] = excl; excl += local[j]; }
}
__global__ void scatter_k(const float* __restrict__ pos, int* __restrict__ cursor,
                          int* __restrict__ perm) {
  int u = blockIdx.x * 256 + threadIdx.x;
  int dst = atomicAdd(&cursor[cell_of(pos[u * 3], pos[u * 3 + 1], pos[u * 3 + 2])], 1);
  perm[dst] = u;
}

// ---------------- permute pos/offs and sig(->bf16) into sorted order ----------------
__global__ void permute_pv(const float* __restrict__ pos, const float* __restrict__ offs,
                           const int* __restrict__ perm,
                           float* __restrict__ posP, float* __restrict__ offsP) {
  int u = blockIdx.x * 256 + threadIdx.x;
  int o = perm[u];
#pragma unroll
  for (int j = 0; j < 3; ++j) {
    posP[u * 3 + j]  = pos[o * 3 + j];
    offsP[u * 3 + j] = offs[o * 3 + j];
  }
}
__global__ void permute_sig(const float* __restrict__ sig, const int* __restrict__ perm,
                            unsigned short* __restrict__ sigbP) {
  int i = blockIdx.x * 256 + threadIdx.x;     // NU*16 chunks of 8 elems
  int u = i >> 4, c = i & 15;
  int o = perm[u];
  const f32x4* p = (const f32x4*)(sig + o * DD + c * 8);
  f32x4 a = p[0], b = p[1];
  short8 v;
  v[0] = (short)f2b(a[0]); v[1] = (short)f2b(a[1]);
  v[2] = (short)f2b(a[2]); v[3] = (short)f2b(a[3]);
  v[4] = (short)f2b(b[0]); v[5] = (short)f2b(b[1]);
  v[6] = (short)f2b(b[2]); v[7] = (short)f2b(b[3]);
  *(short8*)(sigbP + u * DD + c * 8) = v;
}

// ---------------- plain sig->bf16 (fallback mode 1) ----------------
__global__ void prep_sig(const float* __restrict__ s, unsigned short* __restrict__ sb) {
  int i = (blockIdx.x * 256 + threadIdx.x) * 8;
  const f32x4* p = (const f32x4*)(s + i);
  f32x4 a = p[0], b = p[1];
  short8 o;
  o[0] = (short)f2b(a[0]); o[1] = (short)f2b(a[1]);
  o[2] = (short)f2b(a[2]); o[3] = (short)f2b(a[3]);
  o[4] = (short)f2b(b[0]); o[5] = (short)f2b(b[1]);
  o[6] = (short)f2b(b[2]); o[7] = (short)f2b(b[3]);
  *(short8*)(sb + i) = o;
}

// ---------------- main kernel: 4 waves/block, wave = 32 units x {ev0, ev1} ----------------
// ut0,1 = ev0 unit-groups; ut2,3 = ev1 of the SAME units. No outer ev loop.
// Software pipeline: B-frags for kt+1 prefetched during kt's MFMAs.
template<int MODE>
__global__ __launch_bounds__(256, 2) void atu_main(
    const float* __restrict__ pos, const float* __restrict__ sig,
    const unsigned short* __restrict__ sigb,
    const float* __restrict__ offs, const int* __restrict__ perm,
    const float* __restrict__ b1, const float* __restrict__ b2,
    const unsigned short* __restrict__ fpad,
    const short8* __restrict__ w1f, const short8* __restrict__ w2f,
    float* __restrict__ out_stab, float* __restrict__ out_pos)
{
  __shared__ unsigned short hs[4][8192];     // 16KB per wave (64 unit-ev cols), 64KB total
  const int tid  = threadIdx.x;
  const int wid  = tid >> 6, lane = tid & 63;
  const int lg   = lane >> 4, lm = lane & 15;
  const int ubase = blockIdx.x * 128 + wid * 32;   // 32 units per wave, x2 evs
  char* hsb = (char*)&hs[wid][0];
  const char* fpadb = (const char*)fpad;

  // ---- gather bases: ut&1 = unit group, ut>>1 = ev ----
  int abase[4];
#pragma unroll
  for (int ut = 0; ut < 4; ++ut) {
    int u = ubase + (ut & 1) * 16 + lm;
    float px = pos[u * 3 + 0], py = pos[u * 3 + 1], pz = pos[u * 3 + 2];
    if (ut >= 2) { px += offs[u * 3 + 0]; py += offs[u * 3 + 1]; pz += offs[u * 3 + 2]; }
    int pcx = min(max((int)px, 0), GG - 1);
    int pcy = min(max((int)py, 0), GG - 1);
    int pcz = min(max((int)pz, 0), GG - 1);
    abase[ut] = ((pcx + 3) * PG + (pcy + 3)) * PG + (pcz + 3);
  }

#define FETCH_SIG(KT, DST)                                                        \
  {                                                                               \
    int kk = (KT);                                                                \
    _Pragma("unroll")                                                             \
    for (int ug = 0; ug < 2; ++ug) {                                              \
      int u = ubase + ug * 16 + lm;                                               \
      if constexpr (MODE >= 1) {                                                  \
        DST[ug] = *(const short8*)(sigb + u * DD + kk * 32 + lg * 8);             \
      } else {                                                                    \
        const f32x4* sp = (const f32x4*)(sig + (u * DD + kk * 32 + lg * 8));      \
        f32x4 s0 = sp[0], s1 = sp[1];                                             \
        short8 fr;                                                                \
        fr[0] = (short)f2b(s0[0]); fr[1] = (short)f2b(s0[1]);                     \
        fr[2] = (short)f2b(s0[2]); fr[3] = (short)f2b(s0[3]);                     \
        fr[4] = (short)f2b(s1[0]); fr[5] = (short)f2b(s1[1]);                     \
        fr[6] = (short)f2b(s1[2]); fr[7] = (short)f2b(s1[3]);                     \
        DST[ug] = fr;                                                             \
      }                                                                           \
    }                                                                             \
    DST[2] = DST[0]; DST[3] = DST[1];                                             \
  }

#define FETCH_ROW(KT, DST)                                                        \
  {                                                                               \
    int rd = ROWD.v[((KT) - 4) * 4 + lg];                                         \
    _Pragma("unroll")                                                             \
    for (int ut = 0; ut < 4; ++ut)                                                \
      DST[ut] = *(const short8*)(fpadb + 2 * (abase[ut] + rd));                   \
  }

  // ---- GEMM1: hT[128 feat][64 unit-ev cols], 9 kts, pipelined ----
  f32x4 acc[8][4];
#pragma unroll
  for (int nt = 0; nt < 8; ++nt)
#pragma unroll
    for (int ut = 0; ut < 4; ++ut) acc[nt][ut] = f32x4{0.f, 0.f, 0.f, 0.f};

  {
    short8 curf[4], nxtf[4];
    FETCH_SIG(0, curf);
#pragma unroll 1
    for (int kt = 0; kt < 9; ++kt) {
      if (kt < 3)       FETCH_SIG(kt + 1, nxtf)
      else if (kt < 8)  FETCH_ROW(kt + 1, nxtf)
      short8 af8[8];
#pragma unroll
      for (int nt = 0; nt < 8; ++nt) af8[nt] = w1f[(kt * 8 + nt) * 64 + lane];
#pragma unroll
      for (int nt = 0; nt < 8; ++nt)
#pragma unroll
        for (int ut = 0; ut < 4; ++ut)
          acc[nt][ut] = __builtin_amdgcn_mfma_f32_16x16x32_bf16(af8[nt], curf[ut], acc[nt][ut], 0, 0, 0);
      if (kt < 8) {
#pragma unroll
        for (int ut = 0; ut < 4; ++ut) curf[ut] = nxtf[ut];
      }
    }
  }

  // ---- bias + tanh + write h to swizzled per-wave LDS (transpose) ----
#pragma unroll
  for (int nt = 0; nt < 8; ++nt) {
    f32x4 b1v = *(const f32x4*)(b1 + nt * 16 + lg * 4);
#pragma unroll
    for (int ut = 0; ut < 4; ++ut) {
      int u = ut * 16 + lm;
      float h0 = fast_tanh(acc[nt][ut][0] + b1v[0]);
      float h1 = fast_tanh(acc[nt][ut][1] + b1v[1]);
      float h2 = fast_tanh(acc[nt][ut][2] + b1v[2]);
      float h3 = fast_tanh(acc[nt][ut][3] + b1v[3]);
      unsigned q0 = (unsigned)f2b(h0) | ((unsigned)f2b(h1) << 16);
      unsigned q1 = (unsigned)f2b(h2) | ((unsigned)f2b(h3) << 16);
      int byte = (u * 256 + nt * 32 + lg * 8) ^ ((u & 7) << 4);
      *(unsigned long long*)(hsb + byte) =
          (unsigned long long)q0 | ((unsigned long long)q1 << 32);
    }
  }

  // ---- GEMM2 single-pass (acc2[8][4]) + fused norm, pipelined LDS reads ----
  float ssq[4] = {0.f, 0.f, 0.f, 0.f};
  {
    f32x4 acc2[8][4];
#pragma unroll
    for (int nt = 0; nt < 8; ++nt)
#pragma unroll
      for (int ut = 0; ut < 4; ++ut) acc2[nt][ut] = f32x4{0.f, 0.f, 0.f, 0.f};

#define LDSF(KT, DST)                                                             \
  {                                                                               \
    int kk = (KT);                                                                \
    _Pragma("unroll")                                                             \
    for (int ut = 0; ut < 4; ++ut) {                                              \
      int u = ut * 16 + lm;                                                       \
      int byte = (u * 256 + kk * 64 + lg * 16) ^ ((u & 7) << 4);                  \
      DST[ut] = *(const short8*)(hsb + byte);                                     \
    }                                                                             \
  }

    short8 hcur[4], hnxt[4];
    LDSF(0, hcur);
#pragma unroll 1
    for (int kt = 0; kt < 4; ++kt) {
      if (kt < 3) LDSF(kt + 1, hnxt);
      short8 af8[8];
#pragma unroll
      for (int nt = 0; nt < 8; ++nt) af8[nt] = w2f[(kt * 8 + nt) * 64 + lane];
#pragma unroll
      for (int nt = 0; nt < 8; ++nt)
#pragma unroll
        for (int ut = 0; ut < 4; ++ut)
          acc2[nt][ut] = __builtin_amdgcn_mfma_f32_16x16x32_bf16(af8[nt], hcur[ut], acc2[nt][ut], 0, 0, 0);
      if (kt < 3) {
#pragma unroll
        for (int ut = 0; ut < 4; ++ut) hcur[ut] = hnxt[ut];
      }
    }

    // ---- || resp - sig ||^2  (sig compare loaded once per unit group) ----
#pragma unroll
    for (int nt = 0; nt < 8; ++nt) {
      f32x4 b2v = *(const f32x4*)(b2 + nt * 16 + lg * 4);
      f32x4 svg[2];
#pragma unroll
      for (int ug = 0; ug < 2; ++ug) {
        int u = ubase + ug * 16 + lm;
        if constexpr (MODE >= 1) {
          short4v hv = *(const short4v*)(sigb + u * DD + nt * 16 + lg * 4);
          svg[ug][0] = b2f((unsigned short)hv[0]); svg[ug][1] = b2f((unsigned short)hv[1]);
          svg[ug][2] = b2f((unsigned short)hv[2]); svg[ug][3] = b2f((unsigned short)hv[3]);
        } else {
          svg[ug] = *(const f32x4*)(sig + (u * DD + nt * 16 + lg * 4));
        }
      }
#pragma unroll
      for (int ut = 0; ut < 4; ++ut) {
#pragma unroll
        for (int r = 0; r < 4; ++r) {
          float d = acc2[nt][ut][r] + b2v[r] - svg[ut & 1][r];
          ssq[ut] = fmaf(d, d, ssq[ut]);
        }
      }
    }
  }

#pragma unroll
  for (int ut = 0; ut < 4; ++ut) {
    ssq[ut] += __shfl_xor(ssq[ut], 16, 64);
    ssq[ut] += __shfl_xor(ssq[ut], 32, 64);
  }

  // ---- accept / outputs: lanes 0..31 own units ubase + (lane&31) ----
  if (lane < 32) {
    float s0 = (lane & 16) ? ssq[1] : ssq[0];   // ev0
    float s1 = (lane & 16) ? ssq[3] : ssq[2];   // ev1
    int ul = ubase + (lane & 31);
    float px = pos[ul * 3 + 0], py = pos[ul * 3 + 1], pz = pos[ul * 3 + 2];
    float ox = offs[ul * 3 + 0], oy = offs[ul * 3 + 1], oz = offs[ul * 3 + 2];
    bool ok = s1 <= s0;
    int pu = (MODE == 2) ? perm[ul] : ul;
    out_stab[pu] = sqrtf(ok ? s1 : s0);
    out_pos[pu * 3 + 0] = ok ? px + ox : px;
    out_pos[pu * 3 + 1] = ok ? py + oy : py;
    out_pos[pu * 3 + 2] = ok ? pz + oz : pz;
  }
}

extern "C" void kernel_launch(void* const* d_in, const int* in_sizes, int n_in,
                              void* d_out, int out_size, void* d_ws, size_t ws_size,
                              hipStream_t stream) {
  const float* field = (const float*)d_in[0];
  const float* pos   = (const float*)d_in[1];
  const float* sig   = (const float*)d_in[2];
  const float* offs  = (const float*)d_in[3];
  const float* W1    = (const float*)d_in[4];
  const float* b1    = (const float*)d_in[5];
  const float* W2    = (const float*)d_in[6];
  const float* b2    = (const float*)d_in[7];
  float* out_stab = (float*)d_out;
  float* out_pos  = out_stab + NU;

  char* ws = (char*)d_ws;
  unsigned short* fpad  = (unsigned short*)ws;                    // 4,812,208 B (+slack)
  unsigned short* w1t   = (unsigned short*)(ws + 4812800);        // 73,728 B (9 kt)
  unsigned short* w2t   = (unsigned short*)(ws + 4886528);        // 32,768 B
  unsigned short* sigbP = (unsigned short*)(ws + 4919296);        // 67,108,864 B
  float*          posP  = (float*)(ws + 72028160);                // 3,145,728 B
  float*          offsP = (float*)(ws + 75173888);                // 3,145,728 B
  int*            perm  = (int*)(ws + 78319616);                  // 1,048,576 B
  int*            cursor= (int*)(ws + 79368192);                  // 16,384 B
  const size_t need2 = 79384576ull;
  const size_t need1 = 72028160ull;

  prep_field<<<(PG * PG * PG + 255) / 256, 256, 0, stream>>>(field, fpad);
  prep_w<<<26, 256, 0, stream>>>(W1, W2, w1t, w2t);

  if (ws_size >= need2) {
    zero_k<<<NCELL / 256, 256, 0, stream>>>(cursor);
    hist_k<<<NU / 256, 256, 0, stream>>>(pos, cursor);
    scan_k<<<1, 256, 0, stream>>>(cursor);
    scatter_k<<<NU / 256, 256, 0, stream>>>(pos, cursor, perm);
    permute_pv<<<NU / 256, 256, 0, stream>>>(pos, offs, perm, posP, offsP);
    permute_sig<<<NU * 16 / 256, 256, 0, stream>>>(sig, perm, sigbP);
    atu_main<2><<<NU / 128, 256, 0, stream>>>(posP, sig, sigbP, offsP, perm, b1, b2, fpad,
                                              (const short8*)w1t, (const short8*)w2t,
                                              out_stab, out_pos);
  } else if (ws_size >= need1) {
    prep_sig<<<NU * DD / 8 / 256, 256, 0, stream>>>(sig, sigbP);
    atu_main<1><<<NU / 128, 256, 0, stream>>>(pos, sig, sigbP, offs, nullptr, b1, b2, fpad,
                                              (const short8*)w1t, (const short8*)w2t,
                                              out_stab, out_pos);
  } else {
    atu_main<0><<<NU / 128, 256, 0, stream>>>(pos, sig, nullptr, offs, nullptr, b1, b2, fpad,
                                              (const short8*)w1t, (const short8*)w2t,
                                              out_stab, out_pos);
  }
}